// Round 4
// baseline (462.127 us; speedup 1.0000x reference)
//
#include <hip/hip_runtime.h>
#include <hip/hip_bf16.h>
#include <hip/hip_cooperative_groups.h>
#include <math.h>

#define D 768
#define NCLS 96
#define M 8192            // 32*256 tokens
#define NROWS (M + NCLS)  // 8288 grouped rows
#define EPS 1e-5f

// mega (cooperative) k4 geometry: 2 blocks/CU co-residency
#define KBm 192
#define SEGRm 24          // KBm/8 16B segments
#define MAXRm 160
#define DYNLDS (MAXRm * KBm * 2)   // 61440 B

// fallback (round-3) k4 geometry
#define KBf 384
#define SEGRf 48
#define MAXRf 160

typedef __attribute__((ext_vector_type(8))) short bf16x8;
typedef __attribute__((ext_vector_type(4))) float f32x4;

namespace cg = cooperative_groups;

// ==================== cooperative mega-kernel ====================
__global__ __launch_bounds__(256, 2) void mega(
        const float* __restrict__ input_f, const float* __restrict__ cdic,
        const float* __restrict__ gamma, const float* __restrict__ beta,
        const int* __restrict__ labels,
        __hip_bfloat16* __restrict__ xgbh, int* __restrict__ perm,
        int* __restrict__ counts, int* __restrict__ gofs,
        float* __restrict__ cd, float* __restrict__ posp,
        float* __restrict__ negp, double* __restrict__ sd,
        float* __restrict__ out) {
    extern __shared__ char smem[];
    const int bid = blockIdx.x, nb = gridDim.x;
    const int tid = threadIdx.x, wave = tid >> 6, lane = tid & 63;

    // ---------------- P0: counts / gofs / perm / dict-row copy (blocks 0..95) ---
    if (bid < NCLS) {
        int c = bid;
        int* labs  = (int*)smem;                 // 32 KB
        int* ccnt  = (int*)(smem + 33024);
        int* cbase = ccnt + 128;
        int* ltred = cbase + 128;
        int* gshp  = ltred + 4;
        for (int t = tid; t < M / 4; t += 256)
            ((int4*)labs)[t] = ((const int4*)labels)[t];
        __syncthreads();
        int lt0 = 0;
        for (int ch = wave; ch < 128; ch += 4) {
            int lab = labs[ch * 64 + lane];
            unsigned long long meq = __ballot(lab == c);
            unsigned long long mlt = __ballot(lab < c);
            if (lane == 0) { ccnt[ch] = __popcll(meq); lt0 += __popcll(mlt); }
        }
        if (lane == 0) ltred[wave] = lt0;
        __syncthreads();
        if (wave == 0) {
            int v0 = ccnt[lane], v1 = ccnt[64 + lane];
            int s0 = v0;
#pragma unroll
            for (int o = 1; o < 64; o <<= 1) { int t0 = __shfl_up(s0, o); if (lane >= o) s0 += t0; }
            int tot0 = __shfl(s0, 63);
            int s1 = v1;
#pragma unroll
            for (int o = 1; o < 64; o <<= 1) { int t1 = __shfl_up(s1, o); if (lane >= o) s1 += t1; }
            cbase[lane] = s0 - v0;
            cbase[64 + lane] = tot0 + s1 - v1;
            if (lane == 63) {
                counts[c] = tot0 + s1;
                int g = c + ltred[0] + ltred[1] + ltred[2] + ltred[3];
                gofs[c] = g;
                *gshp = g;
            }
        }
        __syncthreads();
        int g = *gshp;
        for (int ch = wave; ch < 128; ch += 4) {
            int m = ch * 64 + lane;
            bool match = (labs[m] == c);
            unsigned long long mask = __ballot(match);
            int pre = __popcll(mask & ((1ull << lane) - 1ull));
            if (match) perm[m] = g + 1 + cbase[ch] + pre;
        }
        for (int t = tid; t < D; t += 256)
            xgbh[(size_t)g * D + t] = __float2bfloat16(cdic[c * D + t]);
    }
    __threadfence();
    cg::this_grid().sync();

    // ---------------- P1: LayerNorm + bf16 scatter (all blocks) -----------------
    {
        int rpb = M / nb;
        for (int i = 0; i < rpb; i += 4) {
            int row = bid * rpb + i + wave;
            const float* xr = input_f + (size_t)row * D;
            float4 v[3];
            float s = 0.f, sq = 0.f;
#pragma unroll
            for (int t = 0; t < 3; ++t) {
                v[t] = *(const float4*)(xr + (lane + 64 * t) * 4);
                s  += v[t].x + v[t].y + v[t].z + v[t].w;
                sq += v[t].x * v[t].x + v[t].y * v[t].y + v[t].z * v[t].z + v[t].w * v[t].w;
            }
#pragma unroll
            for (int o = 32; o; o >>= 1) { s += __shfl_xor(s, o); sq += __shfl_xor(sq, o); }
            float mu   = s / (float)D;
            float var  = sq / (float)D - mu * mu;
            float rstd = rsqrtf(var + EPS);
            int dest = perm[row];
            unsigned short* orow = (unsigned short*)xgbh + (size_t)dest * D;
#pragma unroll
            for (int t = 0; t < 3; ++t) {
                int base = (lane + 64 * t) * 4;
                float4 g4 = *(const float4*)(gamma + base);
                float4 b4 = *(const float4*)(beta + base);
                float f0 = (v[t].x - mu) * rstd * g4.x + b4.x;
                float f1 = (v[t].y - mu) * rstd * g4.y + b4.y;
                float f2 = (v[t].z - mu) * rstd * g4.z + b4.z;
                float f3 = (v[t].w - mu) * rstd * g4.w + b4.w;
                __hip_bfloat16 h0 = __float2bfloat16(f0), h1 = __float2bfloat16(f1);
                __hip_bfloat16 h2 = __float2bfloat16(f2), h3 = __float2bfloat16(f3);
                ushort4 u;
                u.x = *(unsigned short*)&h0; u.y = *(unsigned short*)&h1;
                u.z = *(unsigned short*)&h2; u.w = *(unsigned short*)&h3;
                *(ushort4*)(orow + base) = u;
            }
        }
    }
    __threadfence();
    cg::this_grid().sync();

    // ---------------- P2: gram (blocks 0..95) || cd (blocks 96..190) ------------
    if (bid < NCLS) {
        const unsigned short* xgb = (const unsigned short*)xgbh;
        unsigned short* sh = (unsigned short*)smem;      // [MAXRm][KBm] swizzled
        int c = bid;
        int r0 = gofs[c];
        int nc = counts[c] + 1;
        int ntile = (nc + 31) >> 5;
        int nr = ntile << 5;
        int tott = ntile * (ntile + 1) / 2;
        int s_ti[4], s_tj[4];
#pragma unroll
        for (int slot = 0; slot < 4; ++slot) {
            int t = wave + slot * 4;
            int ti = 0, rem = t, span = ntile;
            if (t < tott) {
                while (rem >= span) { rem -= span; --span; ++ti; }
                s_ti[slot] = ti; s_tj[slot] = ti + rem;
            } else { s_ti[slot] = 0; s_tj[slot] = 0; }
        }
        int r16 = lane & 15, sA = lane >> 4;
        int xr = r16 & 7;
        int e0 = (sA ^ xr) * 8;
        int e1 = ((sA + 4) ^ xr) * 8;
        f32x4 acc[4][4];
#pragma unroll
        for (int s = 0; s < 4; ++s)
#pragma unroll
            for (int q = 0; q < 4; ++q) acc[s][q] = f32x4{0.f, 0.f, 0.f, 0.f};

        for (int kc = 0; kc < D; kc += KBm) {            // 4 K-chunks
            __syncthreads();
            int totseg = nr * SEGRm;
            for (int seg = tid; seg < totseg; seg += 256) {
                int r = seg / SEGRm, s = seg - r * SEGRm;
                uint4 v = {0u, 0u, 0u, 0u};
                if (r < nc)
                    v = *(const uint4*)(xgb + (size_t)(r0 + r) * D + kc + s * 8);
                *(uint4*)(sh + r * KBm + (s ^ (r & 7)) * 8) = v;
            }
            __syncthreads();
#pragma unroll
            for (int slot = 0; slot < 4; ++slot) {
                if (wave + slot * 4 >= tott) continue;
                int ti = s_ti[slot], tj = s_tj[slot];
                const unsigned short* pa0 = sh + (ti * 32 + r16) * KBm;
                const unsigned short* pa1 = pa0 + 16 * KBm;
                const unsigned short* pb0 = sh + (tj * 32 + r16) * KBm;
                const unsigned short* pb1 = pb0 + 16 * KBm;
#pragma unroll
                for (int ks = 0; ks < KBm / 32; ++ks) {
                    int ko = (ks >> 1) * 64 + ((ks & 1) ? e1 : e0);
                    bf16x8 a0 = *(const bf16x8*)(pa0 + ko);
                    bf16x8 a1 = *(const bf16x8*)(pa1 + ko);
                    bf16x8 b0 = *(const bf16x8*)(pb0 + ko);
                    bf16x8 b1 = *(const bf16x8*)(pb1 + ko);
                    acc[slot][0] = __builtin_amdgcn_mfma_f32_16x16x32_bf16(a0, b0, acc[slot][0], 0, 0, 0);
                    acc[slot][1] = __builtin_amdgcn_mfma_f32_16x16x32_bf16(a0, b1, acc[slot][1], 0, 0, 0);
                    acc[slot][2] = __builtin_amdgcn_mfma_f32_16x16x32_bf16(a1, b0, acc[slot][2], 0, 0, 0);
                    acc[slot][3] = __builtin_amdgcn_mfma_f32_16x16x32_bf16(a1, b1, acc[slot][3], 0, 0, 0);
                }
            }
        }
        const float inv = 1.f / (float)D;
        float tacc = 0.f;
        int rbase = sA * 4;
#pragma unroll
        for (int slot = 0; slot < 4; ++slot) {
            if (wave + slot * 4 >= tott) continue;
            int ti = s_ti[slot], tj = s_tj[slot];
            float w = (ti == tj) ? 1.f : 2.f;
#pragma unroll
            for (int fa = 0; fa < 2; ++fa)
#pragma unroll
                for (int fb = 0; fb < 2; ++fb)
#pragma unroll
                    for (int reg = 0; reg < 4; ++reg) {
                        int i = ti * 32 + fa * 16 + rbase + reg;
                        int j = tj * 32 + fb * 16 + r16;
                        if (i < nc && j < nc)
                            tacc += w * __expf(acc[slot][fa * 2 + fb][reg] * inv);
                    }
        }
#pragma unroll
        for (int o = 32; o; o >>= 1) tacc += __shfl_xor(tacc, o);
        __syncthreads();                    // all LDS reads done before smem reuse
        float* red = (float*)smem;
        if (lane == 0) red[wave] = tacc;
        __syncthreads();
        if (tid == 0) posp[c] = red[0] + red[1] + red[2] + red[3];
    } else if (bid < NCLS + 95) {
        int c = bid - NCLS + 1;             // 1..95
        const __hip_bfloat16* xgb = (const __hip_bfloat16*)xgbh;
        int n = counts[c];
        const __hip_bfloat16* rows = xgb + (size_t)(gofs[c] + 1) * D;
        float p0[3] = {0,0,0}, p1[3] = {0,0,0}, p2[3] = {0,0,0}, p3[3] = {0,0,0};
        int r = 0;
        for (; r + 4 <= n; r += 4) {
            const __hip_bfloat16* r0 = rows + (size_t)r * D;
            const __hip_bfloat16* r1 = r0 + D;
            const __hip_bfloat16* r2 = r1 + D;
            const __hip_bfloat16* r3 = r2 + D;
            p0[0] += __bfloat162float(r0[tid]); p0[1] += __bfloat162float(r0[tid + 256]); p0[2] += __bfloat162float(r0[tid + 512]);
            p1[0] += __bfloat162float(r1[tid]); p1[1] += __bfloat162float(r1[tid + 256]); p1[2] += __bfloat162float(r1[tid + 512]);
            p2[0] += __bfloat162float(r2[tid]); p2[1] += __bfloat162float(r2[tid + 256]); p2[2] += __bfloat162float(r2[tid + 512]);
            p3[0] += __bfloat162float(r3[tid]); p3[1] += __bfloat162float(r3[tid + 256]); p3[2] += __bfloat162float(r3[tid + 512]);
        }
        for (; r < n; ++r) {
            const __hip_bfloat16* r0 = rows + (size_t)r * D;
            p0[0] += __bfloat162float(r0[tid]); p0[1] += __bfloat162float(r0[tid + 256]); p0[2] += __bfloat162float(r0[tid + 512]);
        }
        float s0 = (p0[0] + p1[0]) + (p2[0] + p3[0]);
        float s1 = (p0[1] + p1[1]) + (p2[1] + p3[1]);
        float s2 = (p0[2] + p1[2]) + (p2[2] + p3[2]);
        float invn = 1.f / ((float)n + 1.f);
        float c0 = cdic[c * D + tid], c1 = cdic[c * D + tid + 256], c2 = cdic[c * D + tid + 512];
        float u0 = c0 + 0.1f * (c0 + s0) * invn;
        float u1 = c1 + 0.1f * (c1 + s1) * invn;
        float u2 = c2 + 0.1f * (c2 + s2) * invn;
        float s = u0 + u1 + u2, sq = u0 * u0 + u1 * u1 + u2 * u2;
#pragma unroll
        for (int o = 32; o; o >>= 1) { s += __shfl_xor(s, o); sq += __shfl_xor(sq, o); }
        float* red = (float*)smem;
        if (lane == 0) { red[wave] = s; red[4 + wave] = sq; }
        __syncthreads();
        if (tid == 0) {
            red[0] = red[0] + red[1] + red[2] + red[3];
            red[4] = red[4] + red[5] + red[6] + red[7];
        }
        __syncthreads();
        float mu   = red[0] / (float)D;
        float var  = red[4] / (float)D - mu * mu;
        float rstd = rsqrtf(var + EPS);
        float* outr = cd + (size_t)(c - 1) * D;
        outr[tid]       = (u0 - mu) * rstd * gamma[tid]       + beta[tid];
        outr[tid + 256] = (u1 - mu) * rstd * gamma[tid + 256] + beta[tid + 256];
        outr[tid + 512] = (u2 - mu) * rstd * gamma[tid + 512] + beta[tid + 512];
    }
    __threadfence();
    cg::this_grid().sync();

    // ---------------- P3: neg gram (blocks 0..94) + posp reduce (block 95) ------
    if (bid < 95) {
        float* rowi = (float*)smem;
        float* red  = (float*)(smem + 3072);
        int i = bid;
        for (int t = tid; t < D; t += 256) rowi[t] = cd[(size_t)i * D + t];
        __syncthreads();
        float acc = 0.f;
        for (int j = wave; j < 95; j += 4) {
            const float* rj = cd + (size_t)j * D;
            float dot = 0.f;
#pragma unroll
            for (int t = 0; t < 12; ++t) dot += rowi[lane + 64 * t] * rj[lane + 64 * t];
#pragma unroll
            for (int o = 32; o; o >>= 1) dot += __shfl_xor(dot, o);
            if (lane == 0) acc += __expf(dot * (1.f / (float)D));
        }
        if (lane == 0) red[wave] = acc;
        __syncthreads();
        if (tid == 0) negp[i] = red[0] + red[1] + red[2] + red[3];
    } else if (bid == 95 && wave == 0) {
        double p = (double)posp[lane];
        if (lane < 32) p += (double)posp[64 + lane];
#pragma unroll
        for (int o = 32; o; o >>= 1) p += __shfl_xor(p, o);
        if (lane == 0) sd[0] = p;
    }
    __threadfence();
    cg::this_grid().sync();

    // ---------------- P4: final loss (block 0) ----------------------------------
    if (bid == 0 && wave == 0) {
        double ng = (double)negp[lane] * (lane < 95 ? 1.0 : 0.0);
        if (lane < 31) ng += (double)negp[64 + lane];
#pragma unroll
        for (int o = 32; o; o >>= 1) ng += __shfl_xor(ng, o);
        if (lane == 0) out[0] = (float)(log(ng) - log(sd[0]));
    }
}

// ==================== fallback path (round-3, proven) ====================
__global__ __launch_bounds__(256) void k1_layernorm(const float* __restrict__ x,
        const float* __restrict__ gamma, const float* __restrict__ beta,
        const int* __restrict__ perm, __hip_bfloat16* __restrict__ xgb) {
    int wave = threadIdx.x >> 6;
    int lane = threadIdx.x & 63;
    int row = blockIdx.x * 4 + wave;
    const float* xr = x + (size_t)row * D;
    float4 v[3];
    float s = 0.f, sq = 0.f;
#pragma unroll
    for (int t = 0; t < 3; ++t) {
        v[t] = *(const float4*)(xr + (lane + 64 * t) * 4);
        s  += v[t].x + v[t].y + v[t].z + v[t].w;
        sq += v[t].x * v[t].x + v[t].y * v[t].y + v[t].z * v[t].z + v[t].w * v[t].w;
    }
#pragma unroll
    for (int o = 32; o; o >>= 1) { s += __shfl_xor(s, o); sq += __shfl_xor(sq, o); }
    float mu   = s / (float)D;
    float var  = sq / (float)D - mu * mu;
    float rstd = rsqrtf(var + EPS);
    int dest = perm[row];
    unsigned short* o = (unsigned short*)xgb + (size_t)dest * D;
#pragma unroll
    for (int t = 0; t < 3; ++t) {
        int base = (lane + 64 * t) * 4;
        float4 g = *(const float4*)(gamma + base);
        float4 b = *(const float4*)(beta + base);
        float f0 = (v[t].x - mu) * rstd * g.x + b.x;
        float f1 = (v[t].y - mu) * rstd * g.y + b.y;
        float f2 = (v[t].z - mu) * rstd * g.z + b.z;
        float f3 = (v[t].w - mu) * rstd * g.w + b.w;
        __hip_bfloat16 h0 = __float2bfloat16(f0), h1 = __float2bfloat16(f1);
        __hip_bfloat16 h2 = __float2bfloat16(f2), h3 = __float2bfloat16(f3);
        ushort4 u;
        u.x = *(unsigned short*)&h0; u.y = *(unsigned short*)&h1;
        u.z = *(unsigned short*)&h2; u.w = *(unsigned short*)&h3;
        *(ushort4*)(o + base) = u;
    }
}

__global__ __launch_bounds__(256) void k2_lists(const int* __restrict__ labels,
        const float* __restrict__ cdic, int* __restrict__ perm,
        int* __restrict__ counts, int* __restrict__ gofs,
        __hip_bfloat16* __restrict__ xgb) {
    int c = blockIdx.x;
    int tid = threadIdx.x, wave = tid >> 6, lane = tid & 63;
    __shared__ int labs[M];
    __shared__ int ccnt[128];
    __shared__ int cbase[128];
    __shared__ int ltred[4];
    __shared__ int gsh;
    for (int t = tid; t < M / 4; t += 256)
        ((int4*)labs)[t] = ((const int4*)labels)[t];
    __syncthreads();
    int lt0 = 0;
    for (int ch = wave; ch < 128; ch += 4) {
        int lab = labs[ch * 64 + lane];
        unsigned long long meq = __ballot(lab == c);
        unsigned long long mlt = __ballot(lab < c);
        if (lane == 0) { ccnt[ch] = __popcll(meq); lt0 += __popcll(mlt); }
    }
    if (lane == 0) ltred[wave] = lt0;
    __syncthreads();
    if (wave == 0) {
        int v0 = ccnt[lane], v1 = ccnt[64 + lane];
        int s0 = v0;
#pragma unroll
        for (int o = 1; o < 64; o <<= 1) { int t0 = __shfl_up(s0, o); if (lane >= o) s0 += t0; }
        int tot0 = __shfl(s0, 63);
        int s1 = v1;
#pragma unroll
        for (int o = 1; o < 64; o <<= 1) { int t1 = __shfl_up(s1, o); if (lane >= o) s1 += t1; }
        cbase[lane] = s0 - v0;
        cbase[64 + lane] = tot0 + s1 - v1;
        if (lane == 63) {
            counts[c] = tot0 + s1;
            int g = c + ltred[0] + ltred[1] + ltred[2] + ltred[3];
            gofs[c] = g;
            gsh = g;
        }
    }
    __syncthreads();
    int g = gsh;
    for (int ch = wave; ch < 128; ch += 4) {
        int m = ch * 64 + lane;
        bool match = (labs[m] == c);
        unsigned long long mask = __ballot(match);
        int pre = __popcll(mask & ((1ull << lane) - 1ull));
        if (match) perm[m] = g + 1 + cbase[ch] + pre;
    }
    for (int t = tid; t < D; t += 256)
        xgb[(size_t)g * D + t] = __float2bfloat16(cdic[c * D + t]);
}

__global__ __launch_bounds__(256) void k3_cd(const __hip_bfloat16* __restrict__ xgb,
        const float* __restrict__ cdic, const float* __restrict__ gamma,
        const float* __restrict__ beta, const int* __restrict__ counts,
        const int* __restrict__ gofs, float* __restrict__ cd) {
    int c = blockIdx.x + 1;
    int tid = threadIdx.x;
    int n = counts[c];
    const __hip_bfloat16* rows = xgb + (size_t)(gofs[c] + 1) * D;
    float p0[3] = {0,0,0}, p1[3] = {0,0,0}, p2[3] = {0,0,0}, p3[3] = {0,0,0};
    int r = 0;
    for (; r + 4 <= n; r += 4) {
        const __hip_bfloat16* r0 = rows + (size_t)r * D;
        const __hip_bfloat16* r1 = r0 + D;
        const __hip_bfloat16* r2 = r1 + D;
        const __hip_bfloat16* r3 = r2 + D;
        p0[0] += __bfloat162float(r0[tid]); p0[1] += __bfloat162float(r0[tid + 256]); p0[2] += __bfloat162float(r0[tid + 512]);
        p1[0] += __bfloat162float(r1[tid]); p1[1] += __bfloat162float(r1[tid + 256]); p1[2] += __bfloat162float(r1[tid + 512]);
        p2[0] += __bfloat162float(r2[tid]); p2[1] += __bfloat162float(r2[tid + 256]); p2[2] += __bfloat162float(r2[tid + 512]);
        p3[0] += __bfloat162float(r3[tid]); p3[1] += __bfloat162float(r3[tid + 256]); p3[2] += __bfloat162float(r3[tid + 512]);
    }
    for (; r < n; ++r) {
        const __hip_bfloat16* r0 = rows + (size_t)r * D;
        p0[0] += __bfloat162float(r0[tid]); p0[1] += __bfloat162float(r0[tid + 256]); p0[2] += __bfloat162float(r0[tid + 512]);
    }
    float s0 = (p0[0] + p1[0]) + (p2[0] + p3[0]);
    float s1 = (p0[1] + p1[1]) + (p2[1] + p3[1]);
    float s2 = (p0[2] + p1[2]) + (p2[2] + p3[2]);
    float inv = 1.f / ((float)n + 1.f);
    float c0 = cdic[c * D + tid], c1 = cdic[c * D + tid + 256], c2 = cdic[c * D + tid + 512];
    float u0 = c0 + 0.1f * (c0 + s0) * inv;
    float u1 = c1 + 0.1f * (c1 + s1) * inv;
    float u2 = c2 + 0.1f * (c2 + s2) * inv;
    float s = u0 + u1 + u2, sq = u0 * u0 + u1 * u1 + u2 * u2;
#pragma unroll
    for (int o = 32; o; o >>= 1) { s += __shfl_xor(s, o); sq += __shfl_xor(sq, o); }
    __shared__ float red[8];
    int wave = tid >> 6, lane = tid & 63;
    if (lane == 0) { red[wave] = s; red[4 + wave] = sq; }
    __syncthreads();
    if (tid == 0) {
        red[0] = red[0] + red[1] + red[2] + red[3];
        red[4] = red[4] + red[5] + red[6] + red[7];
    }
    __syncthreads();
    float mu   = red[0] / (float)D;
    float var  = red[4] / (float)D - mu * mu;
    float rstd = rsqrtf(var + EPS);
    float* out = cd + (size_t)(c - 1) * D;
    out[tid]       = (u0 - mu) * rstd * gamma[tid]       + beta[tid];
    out[tid + 256] = (u1 - mu) * rstd * gamma[tid + 256] + beta[tid + 256];
    out[tid + 512] = (u2 - mu) * rstd * gamma[tid + 512] + beta[tid + 512];
}

__global__ __launch_bounds__(256) void k4_pos(const __hip_bfloat16* __restrict__ xgbh,
        const int* __restrict__ counts, const int* __restrict__ gofs,
        float* __restrict__ posp) {
    const unsigned short* xgb = (const unsigned short*)xgbh;
    int c = blockIdx.x;
    int tid = threadIdx.x, wave = tid >> 6, lane = tid & 63;
    extern __shared__ unsigned short sh[];
    int r0 = gofs[c];
    int nc = counts[c] + 1;
    int ntile = (nc + 31) >> 5;
    int nr = ntile << 5;
    int tott = ntile * (ntile + 1) / 2;
    int s_ti[4], s_tj[4];
#pragma unroll
    for (int slot = 0; slot < 4; ++slot) {
        int t = wave + slot * 4;
        int ti = 0, rem = t, span = ntile;
        if (t < tott) {
            while (rem >= span) { rem -= span; --span; ++ti; }
            s_ti[slot] = ti; s_tj[slot] = ti + rem;
        } else { s_ti[slot] = 0; s_tj[slot] = 0; }
    }
    int r16 = lane & 15, sA = lane >> 4;
    int xr = r16 & 7;
    int e0 = (sA ^ xr) * 8;
    int e1 = ((sA + 4) ^ xr) * 8;
    f32x4 acc[4][4];
#pragma unroll
    for (int s = 0; s < 4; ++s)
#pragma unroll
        for (int q = 0; q < 4; ++q) acc[s][q] = f32x4{0.f, 0.f, 0.f, 0.f};
    for (int kc = 0; kc < D; kc += KBf) {
        __syncthreads();
        int totseg = nr * SEGRf;
        for (int seg = tid; seg < totseg; seg += 256) {
            int r = seg / SEGRf, s = seg - r * SEGRf;
            uint4 v = {0u, 0u, 0u, 0u};
            if (r < nc)
                v = *(const uint4*)(xgb + (size_t)(r0 + r) * D + kc + s * 8);
            *(uint4*)(sh + r * KBf + (s ^ (r & 7)) * 8) = v;
        }
        __syncthreads();
#pragma unroll
        for (int slot = 0; slot < 4; ++slot) {
            if (wave + slot * 4 >= tott) continue;
            int ti = s_ti[slot], tj = s_tj[slot];
            const unsigned short* pa0 = sh + (ti * 32 + r16) * KBf;
            const unsigned short* pa1 = pa0 + 16 * KBf;
            const unsigned short* pb0 = sh + (tj * 32 + r16) * KBf;
            const unsigned short* pb1 = pb0 + 16 * KBf;
#pragma unroll
            for (int ks = 0; ks < KBf / 32; ++ks) {
                int ko = (ks >> 1) * 64 + ((ks & 1) ? e1 : e0);
                bf16x8 a0 = *(const bf16x8*)(pa0 + ko);
                bf16x8 a1 = *(const bf16x8*)(pa1 + ko);
                bf16x8 b0 = *(const bf16x8*)(pb0 + ko);
                bf16x8 b1 = *(const bf16x8*)(pb1 + ko);
                acc[slot][0] = __builtin_amdgcn_mfma_f32_16x16x32_bf16(a0, b0, acc[slot][0], 0, 0, 0);
                acc[slot][1] = __builtin_amdgcn_mfma_f32_16x16x32_bf16(a0, b1, acc[slot][1], 0, 0, 0);
                acc[slot][2] = __builtin_amdgcn_mfma_f32_16x16x32_bf16(a1, b0, acc[slot][2], 0, 0, 0);
                acc[slot][3] = __builtin_amdgcn_mfma_f32_16x16x32_bf16(a1, b1, acc[slot][3], 0, 0, 0);
            }
        }
    }
    const float inv = 1.f / (float)D;
    float tacc = 0.f;
    int rbase = sA * 4;
#pragma unroll
    for (int slot = 0; slot < 4; ++slot) {
        if (wave + slot * 4 >= tott) continue;
        int ti = s_ti[slot], tj = s_tj[slot];
        float w = (ti == tj) ? 1.f : 2.f;
#pragma unroll
        for (int fa = 0; fa < 2; ++fa)
#pragma unroll
            for (int fb = 0; fb < 2; ++fb)
#pragma unroll
                for (int reg = 0; reg < 4; ++reg) {
                    int i = ti * 32 + fa * 16 + rbase + reg;
                    int j = tj * 32 + fb * 16 + r16;
                    if (i < nc && j < nc)
                        tacc += w * __expf(acc[slot][fa * 2 + fb][reg] * inv);
                }
    }
#pragma unroll
    for (int o = 32; o; o >>= 1) tacc += __shfl_xor(tacc, o);
    __shared__ float red[4];
    if (lane == 0) red[wave] = tacc;
    __syncthreads();
    if (tid == 0) posp[c] = red[0] + red[1] + red[2] + red[3];
}

__global__ __launch_bounds__(256) void k5_neg(const float* __restrict__ cd,
        float* __restrict__ negp) {
    int i = blockIdx.x;
    int tid = threadIdx.x, wave = tid >> 6, lane = tid & 63;
    __shared__ float rowi[D];
    for (int t = tid; t < D; t += 256) rowi[t] = cd[(size_t)i * D + t];
    __syncthreads();
    float acc = 0.f;
    for (int j = wave; j < 95; j += 4) {
        const float* rj = cd + (size_t)j * D;
        float dot = 0.f;
#pragma unroll
        for (int t = 0; t < 12; ++t) dot += rowi[lane + 64 * t] * rj[lane + 64 * t];
#pragma unroll
        for (int o = 32; o; o >>= 1) dot += __shfl_xor(dot, o);
        if (lane == 0) acc += __expf(dot * (1.f / (float)D));
    }
    __shared__ float red[4];
    if (lane == 0) red[wave] = acc;
    __syncthreads();
    if (tid == 0) negp[i] = red[0] + red[1] + red[2] + red[3];
}

__global__ __launch_bounds__(256) void k6_final(const float* __restrict__ posp,
        const float* __restrict__ negp, float* __restrict__ out) {
    int tid = threadIdx.x;
    double p = 0.0, ng = 0.0;
    for (int t = tid; t < NCLS; t += 256) p  += (double)posp[t];
    for (int t = tid; t < 95; t += 256)   ng += (double)negp[t];
    __shared__ double rp[256], rn[256];
    rp[tid] = p; rn[tid] = ng;
    __syncthreads();
    for (int s = 128; s; s >>= 1) {
        if (tid < s) { rp[tid] += rp[tid + s]; rn[tid] += rn[tid + s]; }
        __syncthreads();
    }
    if (tid == 0) out[0] = (float)(log(rn[0]) - log(rp[0]));
}

extern "C" void kernel_launch(void* const* d_in, const int* in_sizes, int n_in,
                              void* d_out, int out_size, void* d_ws, size_t ws_size,
                              hipStream_t stream) {
    const float* input_f  = (const float*)d_in[0];
    const float* char_dic = (const float*)d_in[1];
    const float* gamma    = (const float*)d_in[2];
    const float* beta     = (const float*)d_in[3];
    const int*   target   = (const int*)d_in[4];
    float* out = (float*)d_out;

    char* ws = (char*)d_ws;
    size_t off = 0;
    auto carve = [&](size_t bytes) -> void* {
        void* p = ws + off;
        off = (off + bytes + 255) & ~(size_t)255;
        return p;
    };
    __hip_bfloat16* xgb = (__hip_bfloat16*)carve((size_t)(NROWS + 32) * D * 2);
    int*    perm   = (int*)   carve((size_t)M * 4);
    int*    counts = (int*)   carve(NCLS * 4);
    int*    gofs   = (int*)   carve(NCLS * 4);
    float*  cd     = (float*) carve((size_t)95 * D * 4);
    float*  posp   = (float*) carve(NCLS * 4);
    float*  negp   = (float*) carve(95 * 4);
    double* sd     = (double*)carve(64);

    (void)hipFuncSetAttribute((const void*)mega,
            hipFuncAttributeMaxDynamicSharedMemorySize, DYNLDS);
    (void)hipFuncSetAttribute((const void*)k4_pos,
            hipFuncAttributeMaxDynamicSharedMemorySize, MAXRf * KBf * 2);

    int nbpc = 0;
    hipError_t eo = hipOccupancyMaxActiveBlocksPerMultiprocessor(
            &nbpc, (const void*)mega, 256, (size_t)DYNLDS);
    int grid = (eo == hipSuccess && nbpc >= 2) ? 512 : 256;

    void* args[] = { (void*)&input_f, (void*)&char_dic, (void*)&gamma, (void*)&beta,
                     (void*)&target, (void*)&xgb, (void*)&perm, (void*)&counts,
                     (void*)&gofs, (void*)&cd, (void*)&posp, (void*)&negp,
                     (void*)&sd, (void*)&out };
    hipError_t err = hipLaunchCooperativeKernel((const void*)mega, dim3(grid),
            dim3(256), args, (unsigned int)DYNLDS, stream);
    if (err != hipSuccess && grid == 512)
        err = hipLaunchCooperativeKernel((const void*)mega, dim3(256),
                dim3(256), args, (unsigned int)DYNLDS, stream);
    if (err != hipSuccess) {
        // fallback: proven round-3 six-kernel path
        k2_lists<<<NCLS, 256, 0, stream>>>(target, char_dic, perm, counts, gofs, xgb);
        k1_layernorm<<<M / 4, 256, 0, stream>>>(input_f, gamma, beta, perm, xgb);
        k3_cd<<<95, 256, 0, stream>>>(xgb, char_dic, gamma, beta, counts, gofs, cd);
        k4_pos<<<NCLS, 256, MAXRf * KBf * 2, stream>>>(xgb, counts, gofs, posp);
        k5_neg<<<95, 256, 0, stream>>>(cd, negp);
        k6_final<<<1, 256, 0, stream>>>(posp, negp, out);
    }
}

// Round 6
// 79.570 us; speedup vs baseline: 5.8078x; 5.8078x over previous
//
#include <hip/hip_runtime.h>
#include <hip/hip_bf16.h>
#include <math.h>

#define D 768
#define NCLS 96
#define M 8192            // 32*256 tokens
#define NROWS (M + NCLS)  // 8288 grouped rows
#define EPS 1e-5f

// gram geometry (proven round-3)
#define KB 384
#define SEGR 48           // KB/8 16B segments per row-chunk
#define MAXR 160          // max rows per class (dict + tokens); holds for this seed
#define DYN_B (MAXR * KB * 2)   // 122880 B dynamic LDS

typedef __attribute__((ext_vector_type(8))) short bf16x8;
typedef __attribute__((ext_vector_type(4))) float f32x4;

// ==================== kA: LN + self-computed scatter + dict copy ================
// 2048 blocks x 256. Each wave owns one token row m: dest = gofs[c] + 1 + rank,
// computed from LDS-staged labels via ballots (no separate list kernel).
__global__ __launch_bounds__(256) void kA(const float* __restrict__ x,
        const float* __restrict__ cdic, const float* __restrict__ gamma,
        const float* __restrict__ beta, const int* __restrict__ labels,
        __hip_bfloat16* __restrict__ xgb, unsigned int* __restrict__ ticket) {
    int bid = blockIdx.x, tid = threadIdx.x, wave = tid >> 6, lane = tid & 63;
    __shared__ int labs[M];          // 32 KB
    __shared__ int dred[4];
    for (int t = tid; t < M / 4; t += 256)
        ((int4*)labs)[t] = ((const int4*)labels)[t];
    __syncthreads();
    if (bid == 0 && tid == 0) *ticket = 0u;   // reset finish ticket each call

    // --- per-wave: destination for row m ---
    int m = bid * 4 + wave;
    int c = labs[m];
    int full = m >> 6, rem = m & 63;
    int cnt_lt = 0, rank = 0;
    for (int w = 0; w < 128; ++w) {
        int val = labs[w * 64 + lane];
        unsigned long long mlt = __ballot(val < c);
        unsigned long long meq = __ballot(val == c);
        cnt_lt += __popcll(mlt);
        if (w < full) rank += __popcll(meq);
        else if (w == full) rank += __popcll(meq & ((1ull << rem) - 1ull));
    }
    int dest = c + cnt_lt + 1 + rank;         // gofs[c] + 1 + rank

    // --- LayerNorm row m -> bf16 xgb[dest] ---
    const float* xr = x + (size_t)m * D;
    float4 v[3];
    float s = 0.f, sq = 0.f;
#pragma unroll
    for (int t = 0; t < 3; ++t) {
        v[t] = *(const float4*)(xr + (lane + 64 * t) * 4);
        s  += v[t].x + v[t].y + v[t].z + v[t].w;
        sq += v[t].x * v[t].x + v[t].y * v[t].y + v[t].z * v[t].z + v[t].w * v[t].w;
    }
#pragma unroll
    for (int o = 32; o; o >>= 1) { s += __shfl_xor(s, o); sq += __shfl_xor(sq, o); }
    float mu   = s / (float)D;
    float var  = sq / (float)D - mu * mu;
    float rstd = rsqrtf(var + EPS);
    unsigned short* orow = (unsigned short*)xgb + (size_t)dest * D;
#pragma unroll
    for (int t = 0; t < 3; ++t) {
        int base = (lane + 64 * t) * 4;
        float4 g4 = *(const float4*)(gamma + base);
        float4 b4 = *(const float4*)(beta + base);
        float f0 = (v[t].x - mu) * rstd * g4.x + b4.x;
        float f1 = (v[t].y - mu) * rstd * g4.y + b4.y;
        float f2 = (v[t].z - mu) * rstd * g4.z + b4.z;
        float f3 = (v[t].w - mu) * rstd * g4.w + b4.w;
        __hip_bfloat16 h0 = __float2bfloat16(f0), h1 = __float2bfloat16(f1);
        __hip_bfloat16 h2 = __float2bfloat16(f2), h3 = __float2bfloat16(f3);
        ushort4 u;
        u.x = *(unsigned short*)&h0; u.y = *(unsigned short*)&h1;
        u.z = *(unsigned short*)&h2; u.w = *(unsigned short*)&h3;
        *(ushort4*)(orow + base) = u;
    }

    // --- blocks 0..95: raw dict row -> xgb[gofs[c2]] ---
    if (bid < NCLS) {
        int c2 = bid, cl = 0;
        for (int w = wave; w < 128; w += 4)
            cl += __popcll(__ballot(labs[w * 64 + lane] < c2));
        if (lane == 0) dred[wave] = cl;
        __syncthreads();
        int g = c2 + dred[0] + dred[1] + dred[2] + dred[3];
        for (int t = tid; t < D; t += 256)
            xgb[(size_t)g * D + t] = __float2bfloat16(cdic[c2 * D + t]);
    }
}

// ==================== kB: MFMA gram (blocks 0..95) || cd (blocks 96..190) =======
// Each block derives its own (gofs, count) via a 32-iter ballot scan of labels.
__global__ __launch_bounds__(256) void kB(const __hip_bfloat16* __restrict__ xgbh,
        const float* __restrict__ cdic, const float* __restrict__ gamma,
        const float* __restrict__ beta, const int* __restrict__ labels,
        float* __restrict__ posp, float* __restrict__ cd) {
    extern __shared__ unsigned short sh[];   // [MAXR][KB] swizzled (gram role)
    int bid = blockIdx.x, tid = threadIdx.x, wave = tid >> 6, lane = tid & 63;
    int c = (bid < NCLS) ? bid : (bid - NCLS + 1);
    __shared__ int pr[8];
    {
        int cl = 0, ce = 0;
        for (int w = wave; w < 128; w += 4) {
            int val = labels[w * 64 + lane];
            cl += __popcll(__ballot(val < c));
            ce += __popcll(__ballot(val == c));
        }
        if (lane == 0) { pr[wave] = cl; pr[4 + wave] = ce; }
    }
    __syncthreads();
    int r0 = c + pr[0] + pr[1] + pr[2] + pr[3];     // gofs[c]
    int n  = pr[4] + pr[5] + pr[6] + pr[7];         // token count

    if (bid < NCLS) {
        // ---------------- positive gram (round-3 proven body) ----------------
        const unsigned short* xgb = (const unsigned short*)xgbh;
        int nc = n + 1;
        int ntile = (nc + 31) >> 5;
        int nr = ntile << 5;
        int tott = ntile * (ntile + 1) / 2;
        int s_ti[4], s_tj[4];
#pragma unroll
        for (int slot = 0; slot < 4; ++slot) {
            int t = wave + slot * 4;
            int ti = 0, rem = t, span = ntile;
            if (t < tott) {
                while (rem >= span) { rem -= span; --span; ++ti; }
                s_ti[slot] = ti; s_tj[slot] = ti + rem;
            } else { s_ti[slot] = 0; s_tj[slot] = 0; }
        }
        int r16 = lane & 15, sA = lane >> 4;
        int xr = r16 & 7;
        int e0 = (sA ^ xr) * 8;
        int e1 = ((sA + 4) ^ xr) * 8;
        f32x4 acc[4][4];
#pragma unroll
        for (int s = 0; s < 4; ++s)
#pragma unroll
            for (int q = 0; q < 4; ++q) acc[s][q] = f32x4{0.f, 0.f, 0.f, 0.f};
        for (int kc = 0; kc < D; kc += KB) {
            __syncthreads();
            int totseg = nr * SEGR;
            for (int seg = tid; seg < totseg; seg += 256) {
                int r = seg / SEGR, s = seg - r * SEGR;
                uint4 v = {0u, 0u, 0u, 0u};
                if (r < nc)
                    v = *(const uint4*)(xgb + (size_t)(r0 + r) * D + kc + s * 8);
                *(uint4*)(sh + r * KB + (s ^ (r & 7)) * 8) = v;
            }
            __syncthreads();
#pragma unroll
            for (int slot = 0; slot < 4; ++slot) {
                if (wave + slot * 4 >= tott) continue;
                int ti = s_ti[slot], tj = s_tj[slot];
                const unsigned short* pa0 = sh + (ti * 32 + r16) * KB;
                const unsigned short* pa1 = pa0 + 16 * KB;
                const unsigned short* pb0 = sh + (tj * 32 + r16) * KB;
                const unsigned short* pb1 = pb0 + 16 * KB;
#pragma unroll
                for (int ks = 0; ks < KB / 32; ++ks) {
                    int ko = (ks >> 1) * 64 + ((ks & 1) ? e1 : e0);
                    bf16x8 a0 = *(const bf16x8*)(pa0 + ko);
                    bf16x8 a1 = *(const bf16x8*)(pa1 + ko);
                    bf16x8 b0 = *(const bf16x8*)(pb0 + ko);
                    bf16x8 b1 = *(const bf16x8*)(pb1 + ko);
                    acc[slot][0] = __builtin_amdgcn_mfma_f32_16x16x32_bf16(a0, b0, acc[slot][0], 0, 0, 0);
                    acc[slot][1] = __builtin_amdgcn_mfma_f32_16x16x32_bf16(a0, b1, acc[slot][1], 0, 0, 0);
                    acc[slot][2] = __builtin_amdgcn_mfma_f32_16x16x32_bf16(a1, b0, acc[slot][2], 0, 0, 0);
                    acc[slot][3] = __builtin_amdgcn_mfma_f32_16x16x32_bf16(a1, b1, acc[slot][3], 0, 0, 0);
                }
            }
        }
        const float inv = 1.f / (float)D;
        float tacc = 0.f;
        int rbase = sA * 4;
#pragma unroll
        for (int slot = 0; slot < 4; ++slot) {
            if (wave + slot * 4 >= tott) continue;
            int ti = s_ti[slot], tj = s_tj[slot];
            float w = (ti == tj) ? 1.f : 2.f;
#pragma unroll
            for (int fa = 0; fa < 2; ++fa)
#pragma unroll
                for (int fb = 0; fb < 2; ++fb)
#pragma unroll
                    for (int reg = 0; reg < 4; ++reg) {
                        int i = ti * 32 + fa * 16 + rbase + reg;
                        int j = tj * 32 + fb * 16 + r16;
                        if (i < nc && j < nc)
                            tacc += w * __expf(acc[slot][fa * 2 + fb][reg] * inv);
                    }
        }
#pragma unroll
        for (int o = 32; o; o >>= 1) tacc += __shfl_xor(tacc, o);
        __syncthreads();
        float* red = (float*)sh;
        if (lane == 0) red[wave] = tacc;
        __syncthreads();
        if (tid == 0) posp[c] = red[0] + red[1] + red[2] + red[3];
    } else {
        // ---------------- cd rows (round-3 proven body, c = 1..95) ------------
        const __hip_bfloat16* rows = xgbh + (size_t)(r0 + 1) * D;
        float p0[3] = {0,0,0}, p1[3] = {0,0,0}, p2[3] = {0,0,0}, p3[3] = {0,0,0};
        int r = 0;
        for (; r + 4 <= n; r += 4) {
            const __hip_bfloat16* r0p = rows + (size_t)r * D;
            const __hip_bfloat16* r1p = r0p + D;
            const __hip_bfloat16* r2p = r1p + D;
            const __hip_bfloat16* r3p = r2p + D;
            p0[0] += __bfloat162float(r0p[tid]); p0[1] += __bfloat162float(r0p[tid + 256]); p0[2] += __bfloat162float(r0p[tid + 512]);
            p1[0] += __bfloat162float(r1p[tid]); p1[1] += __bfloat162float(r1p[tid + 256]); p1[2] += __bfloat162float(r1p[tid + 512]);
            p2[0] += __bfloat162float(r2p[tid]); p2[1] += __bfloat162float(r2p[tid + 256]); p2[2] += __bfloat162float(r2p[tid + 512]);
            p3[0] += __bfloat162float(r3p[tid]); p3[1] += __bfloat162float(r3p[tid + 256]); p3[2] += __bfloat162float(r3p[tid + 512]);
        }
        for (; r < n; ++r) {
            const __hip_bfloat16* r0p = rows + (size_t)r * D;
            p0[0] += __bfloat162float(r0p[tid]); p0[1] += __bfloat162float(r0p[tid + 256]); p0[2] += __bfloat162float(r0p[tid + 512]);
        }
        float s0 = (p0[0] + p1[0]) + (p2[0] + p3[0]);
        float s1 = (p0[1] + p1[1]) + (p2[1] + p3[1]);
        float s2 = (p0[2] + p1[2]) + (p2[2] + p3[2]);
        float invn = 1.f / ((float)n + 1.f);
        float c0 = cdic[c * D + tid], c1 = cdic[c * D + tid + 256], c2v = cdic[c * D + tid + 512];
        float u0 = c0 + 0.1f * (c0 + s0) * invn;
        float u1 = c1 + 0.1f * (c1 + s1) * invn;
        float u2 = c2v + 0.1f * (c2v + s2) * invn;
        float s = u0 + u1 + u2, sq = u0 * u0 + u1 * u1 + u2 * u2;
#pragma unroll
        for (int o = 32; o; o >>= 1) { s += __shfl_xor(s, o); sq += __shfl_xor(sq, o); }
        float* red = (float*)sh;
        if (lane == 0) { red[wave] = s; red[4 + wave] = sq; }
        __syncthreads();
        if (tid == 0) {
            red[0] = red[0] + red[1] + red[2] + red[3];
            red[4] = red[4] + red[5] + red[6] + red[7];
        }
        __syncthreads();
        float mu   = red[0] / (float)D;
        float var  = red[4] / (float)D - mu * mu;
        float rstd = rsqrtf(var + EPS);
        float* outr = cd + (size_t)(c - 1) * D;
        outr[tid]       = (u0 - mu) * rstd * gamma[tid]       + beta[tid];
        outr[tid + 256] = (u1 - mu) * rstd * gamma[tid + 256] + beta[tid + 256];
        outr[tid + 512] = (u2 - mu) * rstd * gamma[tid + 512] + beta[tid + 512];
    }
}

// ==================== kC: neg gram + ticket-gated final loss ====================
__global__ __launch_bounds__(256) void kC(const float* __restrict__ cd,
        const float* __restrict__ posp, unsigned int* __restrict__ negbits,
        unsigned int* __restrict__ ticket, float* __restrict__ out) {
    int i = blockIdx.x;    // 0..94
    int tid = threadIdx.x, wave = tid >> 6, lane = tid & 63;
    __shared__ float rowi[D];
    __shared__ float red[4];
    __shared__ int winner;
    for (int t = tid; t < D; t += 256) rowi[t] = cd[(size_t)i * D + t];
    __syncthreads();
    float acc = 0.f;
    for (int j = wave; j < 95; j += 4) {
        const float* rj = cd + (size_t)j * D;
        float dot = 0.f;
#pragma unroll
        for (int t = 0; t < 12; ++t) dot += rowi[lane + 64 * t] * rj[lane + 64 * t];
#pragma unroll
        for (int o = 32; o; o >>= 1) dot += __shfl_xor(dot, o);
        if (lane == 0) acc += __expf(dot * (1.f / (float)D));
    }
    if (lane == 0) red[wave] = acc;
    __syncthreads();
    if (tid == 0) {
        float val = red[0] + red[1] + red[2] + red[3];
        atomicExch(&negbits[i], __float_as_uint(val));   // device-scope publish
        __threadfence();
        winner = (atomicAdd(ticket, 1u) == 94u) ? 1 : 0; // 95th finisher wins
    }
    __syncthreads();
    if (winner && wave == 0) {
        __threadfence();                                 // acquire others' publishes
        double ng = (lane < 95)
            ? (double)__uint_as_float(atomicOr(&negbits[lane], 0u)) : 0.0;
        if (lane < 31)                                   // FIX: second chunk 64..94
            ng += (double)__uint_as_float(atomicOr(&negbits[64 + lane], 0u));
        double p = (double)posp[lane];
        if (lane < 32) p += (double)posp[64 + lane];
#pragma unroll
        for (int o = 32; o; o >>= 1) {
            ng += __shfl_xor(ng, o);
            p  += __shfl_xor(p, o);
        }
        if (lane == 0) out[0] = (float)(log(ng) - log(p));
    }
}

extern "C" void kernel_launch(void* const* d_in, const int* in_sizes, int n_in,
                              void* d_out, int out_size, void* d_ws, size_t ws_size,
                              hipStream_t stream) {
    const float* input_f  = (const float*)d_in[0];
    const float* char_dic = (const float*)d_in[1];
    const float* gamma    = (const float*)d_in[2];
    const float* beta     = (const float*)d_in[3];
    const int*   target   = (const int*)d_in[4];
    float* out = (float*)d_out;

    char* ws = (char*)d_ws;
    size_t off = 0;
    auto carve = [&](size_t bytes) -> void* {
        void* p = ws + off;
        off = (off + bytes + 255) & ~(size_t)255;
        return p;
    };
    __hip_bfloat16* xgb = (__hip_bfloat16*)carve((size_t)(NROWS + 32) * D * 2); // 12.8 MB
    float*        posp    = (float*)carve(NCLS * 4);
    float*        cd      = (float*)carve((size_t)95 * D * 4);
    unsigned int* negbits = (unsigned int*)carve(95 * 4);
    unsigned int* ticket  = (unsigned int*)carve(64);

    (void)hipFuncSetAttribute((const void*)kB,
            hipFuncAttributeMaxDynamicSharedMemorySize, DYN_B);

    kA<<<M / 4, 256, 0, stream>>>(input_f, char_dic, gamma, beta, target, xgb, ticket);
    kB<<<NCLS + 95, 256, DYN_B, stream>>>(xgb, char_dic, gamma, beta, target, posp, cd);
    kC<<<95, 256, 0, stream>>>(cd, posp, negbits, ticket, out);
}

// Round 7
// 76.862 us; speedup vs baseline: 6.0124x; 1.0352x over previous
//
#include <hip/hip_runtime.h>
#include <hip/hip_bf16.h>
#include <math.h>

#define D 768
#define NCLS 96
#define M 8192            // 32*256 tokens
#define NROWS (M + NCLS)  // 8288 grouped rows
#define EPS 1e-5f

// gram geometry (proven round-3)
#define KB 384
#define SEGR 48           // KB/8 16B segments per row-chunk
#define MAXR 160          // max rows per class (dict + tokens)
#define DYN_B (MAXR * KB * 2)   // 122880 B dynamic LDS

typedef __attribute__((ext_vector_type(8))) short bf16x8;
typedef __attribute__((ext_vector_type(4))) float f32x4;

// ---------------- K2: counts/gofs/perm + dict copy (round-3 proven) -------------
__global__ __launch_bounds__(256) void k2_lists(const int* __restrict__ labels,
        const float* __restrict__ cdic, int* __restrict__ perm,
        int* __restrict__ counts, int* __restrict__ gofs,
        __hip_bfloat16* __restrict__ xgb, unsigned int* __restrict__ ticket) {
    int c = blockIdx.x;
    int tid = threadIdx.x, wave = tid >> 6, lane = tid & 63;
    __shared__ int labs[M];
    __shared__ int ccnt[128];
    __shared__ int cbase[128];
    __shared__ int ltred[4];
    __shared__ int gsh;
    if (c == 0 && tid == 0) *ticket = 0u;     // reset finish ticket each call
    for (int t = tid; t < M / 4; t += 256)
        ((int4*)labs)[t] = ((const int4*)labels)[t];
    __syncthreads();
    int lt0 = 0;
    for (int ch = wave; ch < 128; ch += 4) {
        int lab = labs[ch * 64 + lane];
        unsigned long long meq = __ballot(lab == c);
        unsigned long long mlt = __ballot(lab < c);
        if (lane == 0) { ccnt[ch] = __popcll(meq); lt0 += __popcll(mlt); }
    }
    if (lane == 0) ltred[wave] = lt0;
    __syncthreads();
    if (wave == 0) {
        int v0 = ccnt[lane], v1 = ccnt[64 + lane];
        int s0 = v0;
#pragma unroll
        for (int o = 1; o < 64; o <<= 1) { int t0 = __shfl_up(s0, o); if (lane >= o) s0 += t0; }
        int tot0 = __shfl(s0, 63);
        int s1 = v1;
#pragma unroll
        for (int o = 1; o < 64; o <<= 1) { int t1 = __shfl_up(s1, o); if (lane >= o) s1 += t1; }
        cbase[lane] = s0 - v0;
        cbase[64 + lane] = tot0 + s1 - v1;
        if (lane == 63) {
            counts[c] = tot0 + s1;
            int g = c + ltred[0] + ltred[1] + ltred[2] + ltred[3];
            gofs[c] = g;
            gsh = g;
        }
    }
    __syncthreads();
    int g = gsh;
    for (int ch = wave; ch < 128; ch += 4) {
        int m = ch * 64 + lane;
        bool match = (labs[m] == c);
        unsigned long long mask = __ballot(match);
        int pre = __popcll(mask & ((1ull << lane) - 1ull));
        if (match) perm[m] = g + 1 + cbase[ch] + pre;
    }
    for (int t = tid; t < D; t += 256)
        xgb[(size_t)g * D + t] = __float2bfloat16(cdic[c * D + t]);
}

// ---------------- K1: LayerNorm + bf16 scatter (round-3 proven) -----------------
__global__ __launch_bounds__(256) void k1_layernorm(const float* __restrict__ x,
        const float* __restrict__ gamma, const float* __restrict__ beta,
        const int* __restrict__ perm, __hip_bfloat16* __restrict__ xgb) {
    int wave = threadIdx.x >> 6;
    int lane = threadIdx.x & 63;
    int row = blockIdx.x * 4 + wave;
    const float* xr = x + (size_t)row * D;
    float4 v[3];
    float s = 0.f, sq = 0.f;
#pragma unroll
    for (int t = 0; t < 3; ++t) {
        v[t] = *(const float4*)(xr + (lane + 64 * t) * 4);
        s  += v[t].x + v[t].y + v[t].z + v[t].w;
        sq += v[t].x * v[t].x + v[t].y * v[t].y + v[t].z * v[t].z + v[t].w * v[t].w;
    }
#pragma unroll
    for (int o = 32; o; o >>= 1) { s += __shfl_xor(s, o); sq += __shfl_xor(sq, o); }
    float mu   = s / (float)D;
    float var  = sq / (float)D - mu * mu;
    float rstd = rsqrtf(var + EPS);
    int dest = perm[row];
    unsigned short* orow = (unsigned short*)xgb + (size_t)dest * D;
#pragma unroll
    for (int t = 0; t < 3; ++t) {
        int base = (lane + 64 * t) * 4;
        float4 g4 = *(const float4*)(gamma + base);
        float4 b4 = *(const float4*)(beta + base);
        float f0 = (v[t].x - mu) * rstd * g4.x + b4.x;
        float f1 = (v[t].y - mu) * rstd * g4.y + b4.y;
        float f2 = (v[t].z - mu) * rstd * g4.z + b4.z;
        float f3 = (v[t].w - mu) * rstd * g4.w + b4.w;
        __hip_bfloat16 h0 = __float2bfloat16(f0), h1 = __float2bfloat16(f1);
        __hip_bfloat16 h2 = __float2bfloat16(f2), h3 = __float2bfloat16(f3);
        ushort4 u;
        u.x = *(unsigned short*)&h0; u.y = *(unsigned short*)&h1;
        u.z = *(unsigned short*)&h2; u.w = *(unsigned short*)&h3;
        *(ushort4*)(orow + base) = u;
    }
}

// ---------------- K4CD: gram (MFMA) + fused cd from LDS-staged rows -------------
// Column sums of the staged class rows give the class mean for free (no xgb
// re-read); cd update+LN epilogue runs in the same block.
__global__ __launch_bounds__(256) void k4cd(const __hip_bfloat16* __restrict__ xgbh,
        const float* __restrict__ cdic, const float* __restrict__ gamma,
        const float* __restrict__ beta, const int* __restrict__ counts,
        const int* __restrict__ gofs, float* __restrict__ posp,
        float* __restrict__ cd) {
    const unsigned short* xgb = (const unsigned short*)xgbh;
    int c = blockIdx.x;
    int tid = threadIdx.x, wave = tid >> 6, lane = tid & 63;
    extern __shared__ unsigned short sh[];     // [MAXR][KB] swizzled
    __shared__ float scol[D];                  // token column sums
    __shared__ float red[8];
    int r0 = gofs[c];
    int nc = counts[c] + 1;
    int ntile = (nc + 31) >> 5;
    int nr = ntile << 5;
    int tott = ntile * (ntile + 1) / 2;
    int s_ti[4], s_tj[4];
#pragma unroll
    for (int slot = 0; slot < 4; ++slot) {
        int t = wave + slot * 4;
        int ti = 0, rem = t, span = ntile;
        if (t < tott) {
            while (rem >= span) { rem -= span; --span; ++ti; }
            s_ti[slot] = ti; s_tj[slot] = ti + rem;
        } else { s_ti[slot] = 0; s_tj[slot] = 0; }
    }
    int r16 = lane & 15, sA = lane >> 4;
    int xr = r16 & 7;
    int e0 = (sA ^ xr) * 8;
    int e1 = ((sA + 4) ^ xr) * 8;
    f32x4 acc[4][4];
#pragma unroll
    for (int s = 0; s < 4; ++s)
#pragma unroll
        for (int q = 0; q < 4; ++q) acc[s][q] = f32x4{0.f, 0.f, 0.f, 0.f};

    for (int kc = 0; kc < D; kc += KB) {       // 2 K-chunks
        __syncthreads();
        int totseg = nr * SEGR;
        for (int seg = tid; seg < totseg; seg += 256) {
            int r = seg / SEGR, s = seg - r * SEGR;
            uint4 v = {0u, 0u, 0u, 0u};
            if (r < nc)
                v = *(const uint4*)(xgb + (size_t)(r0 + r) * D + kc + s * 8);
            *(uint4*)(sh + r * KB + (s ^ (r & 7)) * 8) = v;
        }
        __syncthreads();
        // column sums over token rows (r=1..nr-1; pad rows are zero-filled)
        for (int jj = tid; jj < KB; jj += 256) {
            float s0 = 0.f, s1 = 0.f;
            int r = 1;
            for (; r + 2 <= nr; r += 2) {
                int i0 = r * KB + ((((jj >> 3) ^ (r & 7))) << 3) + (jj & 7);
                int i1 = (r + 1) * KB + ((((jj >> 3) ^ ((r + 1) & 7))) << 3) + (jj & 7);
                s0 += __bfloat162float(*(const __hip_bfloat16*)&sh[i0]);
                s1 += __bfloat162float(*(const __hip_bfloat16*)&sh[i1]);
            }
            for (; r < nr; ++r) {
                int i0 = r * KB + ((((jj >> 3) ^ (r & 7))) << 3) + (jj & 7);
                s0 += __bfloat162float(*(const __hip_bfloat16*)&sh[i0]);
            }
            scol[kc + jj] = s0 + s1;
        }
        // MFMA gram over staged chunk
#pragma unroll
        for (int slot = 0; slot < 4; ++slot) {
            if (wave + slot * 4 >= tott) continue;
            int ti = s_ti[slot], tj = s_tj[slot];
            const unsigned short* pa0 = sh + (ti * 32 + r16) * KB;
            const unsigned short* pa1 = pa0 + 16 * KB;
            const unsigned short* pb0 = sh + (tj * 32 + r16) * KB;
            const unsigned short* pb1 = pb0 + 16 * KB;
#pragma unroll
            for (int ks = 0; ks < KB / 32; ++ks) {
                int ko = (ks >> 1) * 64 + ((ks & 1) ? e1 : e0);
                bf16x8 a0 = *(const bf16x8*)(pa0 + ko);
                bf16x8 a1 = *(const bf16x8*)(pa1 + ko);
                bf16x8 b0 = *(const bf16x8*)(pb0 + ko);
                bf16x8 b1 = *(const bf16x8*)(pb1 + ko);
                acc[slot][0] = __builtin_amdgcn_mfma_f32_16x16x32_bf16(a0, b0, acc[slot][0], 0, 0, 0);
                acc[slot][1] = __builtin_amdgcn_mfma_f32_16x16x32_bf16(a0, b1, acc[slot][1], 0, 0, 0);
                acc[slot][2] = __builtin_amdgcn_mfma_f32_16x16x32_bf16(a1, b0, acc[slot][2], 0, 0, 0);
                acc[slot][3] = __builtin_amdgcn_mfma_f32_16x16x32_bf16(a1, b1, acc[slot][3], 0, 0, 0);
            }
        }
    }
    __syncthreads();                           // scol complete, sh reads done

    // ---- cd epilogue (classes 1..95): update + LayerNorm from scol -------------
    if (c >= 1) {
        int n = nc - 1;
        float invn = 1.f / ((float)n + 1.f);
        float c0 = cdic[c * D + tid], c1 = cdic[c * D + tid + 256], c2v = cdic[c * D + tid + 512];
        float u0 = c0 + 0.1f * (c0 + scol[tid]) * invn;
        float u1 = c1 + 0.1f * (c1 + scol[tid + 256]) * invn;
        float u2 = c2v + 0.1f * (c2v + scol[tid + 512]) * invn;
        float s = u0 + u1 + u2, sq = u0 * u0 + u1 * u1 + u2 * u2;
#pragma unroll
        for (int o = 32; o; o >>= 1) { s += __shfl_xor(s, o); sq += __shfl_xor(sq, o); }
        if (lane == 0) { red[wave] = s; red[4 + wave] = sq; }
        __syncthreads();
        if (tid == 0) {
            red[0] = red[0] + red[1] + red[2] + red[3];
            red[4] = red[4] + red[5] + red[6] + red[7];
        }
        __syncthreads();
        float mu   = red[0] / (float)D;
        float var  = red[4] / (float)D - mu * mu;
        float rstd = rsqrtf(var + EPS);
        float* outr = cd + (size_t)(c - 1) * D;
        outr[tid]       = (u0 - mu) * rstd * gamma[tid]       + beta[tid];
        outr[tid + 256] = (u1 - mu) * rstd * gamma[tid + 256] + beta[tid + 256];
        outr[tid + 512] = (u2 - mu) * rstd * gamma[tid + 512] + beta[tid + 512];
    }

    // ---- gram epilogue: exp + block reduce -> posp ------------------------------
    const float inv = 1.f / (float)D;
    float tacc = 0.f;
    int rbase = sA * 4;
#pragma unroll
    for (int slot = 0; slot < 4; ++slot) {
        if (wave + slot * 4 >= tott) continue;
        int ti = s_ti[slot], tj = s_tj[slot];
        float w = (ti == tj) ? 1.f : 2.f;
#pragma unroll
        for (int fa = 0; fa < 2; ++fa)
#pragma unroll
            for (int fb = 0; fb < 2; ++fb)
#pragma unroll
                for (int reg = 0; reg < 4; ++reg) {
                    int i = ti * 32 + fa * 16 + rbase + reg;
                    int j = tj * 32 + fb * 16 + r16;
                    if (i < nc && j < nc)
                        tacc += w * __expf(acc[slot][fa * 2 + fb][reg] * inv);
                }
    }
#pragma unroll
    for (int o = 32; o; o >>= 1) tacc += __shfl_xor(tacc, o);
    __syncthreads();
    float* gred = (float*)sh;
    if (lane == 0) gred[wave] = tacc;
    __syncthreads();
    if (tid == 0) posp[c] = gred[0] + gred[1] + gred[2] + gred[3];
}

// ---------------- kC: neg gram + ticket-gated final loss (round-6 proven) -------
__global__ __launch_bounds__(256) void kC(const float* __restrict__ cd,
        const float* __restrict__ posp, unsigned int* __restrict__ negbits,
        unsigned int* __restrict__ ticket, float* __restrict__ out) {
    int i = blockIdx.x;    // 0..94
    int tid = threadIdx.x, wave = tid >> 6, lane = tid & 63;
    __shared__ float rowi[D];
    __shared__ float red[4];
    __shared__ int winner;
    for (int t = tid; t < D; t += 256) rowi[t] = cd[(size_t)i * D + t];
    __syncthreads();
    float acc = 0.f;
    for (int j = wave; j < 95; j += 4) {
        const float* rj = cd + (size_t)j * D;
        float dot = 0.f;
#pragma unroll
        for (int t = 0; t < 12; ++t) dot += rowi[lane + 64 * t] * rj[lane + 64 * t];
#pragma unroll
        for (int o = 32; o; o >>= 1) dot += __shfl_xor(dot, o);
        if (lane == 0) acc += __expf(dot * (1.f / (float)D));
    }
    if (lane == 0) red[wave] = acc;
    __syncthreads();
    if (tid == 0) {
        float val = red[0] + red[1] + red[2] + red[3];
        atomicExch(&negbits[i], __float_as_uint(val));   // device-scope publish
        __threadfence();
        winner = (atomicAdd(ticket, 1u) == 94u) ? 1 : 0; // 95th finisher wins
    }
    __syncthreads();
    if (winner && wave == 0) {
        __threadfence();                                 // acquire others' publishes
        double ng = (lane < 95)
            ? (double)__uint_as_float(atomicOr(&negbits[lane], 0u)) : 0.0;
        if (lane < 31)
            ng += (double)__uint_as_float(atomicOr(&negbits[64 + lane], 0u));
        double p = (double)posp[lane];
        if (lane < 32) p += (double)posp[64 + lane];
#pragma unroll
        for (int o = 32; o; o >>= 1) {
            ng += __shfl_xor(ng, o);
            p  += __shfl_xor(p, o);
        }
        if (lane == 0) out[0] = (float)(log(ng) - log(p));
    }
}

extern "C" void kernel_launch(void* const* d_in, const int* in_sizes, int n_in,
                              void* d_out, int out_size, void* d_ws, size_t ws_size,
                              hipStream_t stream) {
    const float* input_f  = (const float*)d_in[0];
    const float* char_dic = (const float*)d_in[1];
    const float* gamma    = (const float*)d_in[2];
    const float* beta     = (const float*)d_in[3];
    const int*   target   = (const int*)d_in[4];
    float* out = (float*)d_out;

    char* ws = (char*)d_ws;
    size_t off = 0;
    auto carve = [&](size_t bytes) -> void* {
        void* p = ws + off;
        off = (off + bytes + 255) & ~(size_t)255;
        return p;
    };
    __hip_bfloat16* xgb = (__hip_bfloat16*)carve((size_t)(NROWS + 32) * D * 2); // 12.8 MB
    int*          perm    = (int*)  carve((size_t)M * 4);
    int*          counts  = (int*)  carve(NCLS * 4);
    int*          gofs    = (int*)  carve(NCLS * 4);
    float*        posp    = (float*)carve(NCLS * 4);
    float*        cd      = (float*)carve((size_t)95 * D * 4);
    unsigned int* negbits = (unsigned int*)carve(95 * 4);
    unsigned int* ticket  = (unsigned int*)carve(64);

    (void)hipFuncSetAttribute((const void*)k4cd,
            hipFuncAttributeMaxDynamicSharedMemorySize, DYN_B);

    k2_lists<<<NCLS, 256, 0, stream>>>(target, char_dic, perm, counts, gofs, xgb, ticket);
    k1_layernorm<<<M / 4, 256, 0, stream>>>(input_f, gamma, beta, perm, xgb);
    k4cd<<<NCLS, 256, DYN_B, stream>>>(xgb, char_dic, gamma, beta, counts, gofs, posp, cd);
    kC<<<95, 256, 0, stream>>>(cd, posp, negbits, ticket, out);
}

// Round 8
// 72.252 us; speedup vs baseline: 6.3960x; 1.0638x over previous
//
#include <hip/hip_runtime.h>
#include <hip/hip_bf16.h>
#include <math.h>

#define D 768
#define NCLS 96
#define M 8192            // 32*256 tokens
#define NROWS (M + NCLS)  // 8288 grouped rows
#define EPS 1e-5f

// gram geometry (proven round-3)
#define KB 384
#define SEGR 48           // KB/8 16B segments per row-chunk
#define MAXR 160          // max rows per class (dict + tokens)
#define DYN_B (MAXR * KB * 2)   // 122880 B dynamic LDS

typedef __attribute__((ext_vector_type(8))) short bf16x8;
typedef __attribute__((ext_vector_type(4))) float f32x4;

// ---------------- K2: counts/gofs/perm + dict copy (round-3 proven) -------------
__global__ __launch_bounds__(256) void k2_lists(const int* __restrict__ labels,
        const float* __restrict__ cdic, int* __restrict__ perm,
        int* __restrict__ counts, int* __restrict__ gofs,
        __hip_bfloat16* __restrict__ xgb, unsigned int* __restrict__ ticket) {
    int c = blockIdx.x;
    int tid = threadIdx.x, wave = tid >> 6, lane = tid & 63;
    __shared__ int labs[M];
    __shared__ int ccnt[128];
    __shared__ int cbase[128];
    __shared__ int ltred[4];
    __shared__ int gsh;
    if (c == 0 && tid == 0) *ticket = 0u;     // reset finish ticket each call
    for (int t = tid; t < M / 4; t += 256)
        ((int4*)labs)[t] = ((const int4*)labels)[t];
    __syncthreads();
    int lt0 = 0;
    for (int ch = wave; ch < 128; ch += 4) {
        int lab = labs[ch * 64 + lane];
        unsigned long long meq = __ballot(lab == c);
        unsigned long long mlt = __ballot(lab < c);
        if (lane == 0) { ccnt[ch] = __popcll(meq); lt0 += __popcll(mlt); }
    }
    if (lane == 0) ltred[wave] = lt0;
    __syncthreads();
    if (wave == 0) {
        int v0 = ccnt[lane], v1 = ccnt[64 + lane];
        int s0 = v0;
#pragma unroll
        for (int o = 1; o < 64; o <<= 1) { int t0 = __shfl_up(s0, o); if (lane >= o) s0 += t0; }
        int tot0 = __shfl(s0, 63);
        int s1 = v1;
#pragma unroll
        for (int o = 1; o < 64; o <<= 1) { int t1 = __shfl_up(s1, o); if (lane >= o) s1 += t1; }
        cbase[lane] = s0 - v0;
        cbase[64 + lane] = tot0 + s1 - v1;
        if (lane == 63) {
            counts[c] = tot0 + s1;
            int g = c + ltred[0] + ltred[1] + ltred[2] + ltred[3];
            gofs[c] = g;
            gsh = g;
        }
    }
    __syncthreads();
    int g = gsh;
    for (int ch = wave; ch < 128; ch += 4) {
        int m = ch * 64 + lane;
        bool match = (labs[m] == c);
        unsigned long long mask = __ballot(match);
        int pre = __popcll(mask & ((1ull << lane) - 1ull));
        if (match) perm[m] = g + 1 + cbase[ch] + pre;
    }
    for (int t = tid; t < D; t += 256)
        xgb[(size_t)g * D + t] = __float2bfloat16(cdic[c * D + t]);
}

// ---------------- K1: LayerNorm + bf16 scatter (round-3 proven) -----------------
__global__ __launch_bounds__(256) void k1_layernorm(const float* __restrict__ x,
        const float* __restrict__ gamma, const float* __restrict__ beta,
        const int* __restrict__ perm, __hip_bfloat16* __restrict__ xgb) {
    int wave = threadIdx.x >> 6;
    int lane = threadIdx.x & 63;
    int row = blockIdx.x * 4 + wave;
    const float* xr = x + (size_t)row * D;
    float4 v[3];
    float s = 0.f, sq = 0.f;
#pragma unroll
    for (int t = 0; t < 3; ++t) {
        v[t] = *(const float4*)(xr + (lane + 64 * t) * 4);
        s  += v[t].x + v[t].y + v[t].z + v[t].w;
        sq += v[t].x * v[t].x + v[t].y * v[t].y + v[t].z * v[t].z + v[t].w * v[t].w;
    }
#pragma unroll
    for (int o = 32; o; o >>= 1) { s += __shfl_xor(s, o); sq += __shfl_xor(sq, o); }
    float mu   = s / (float)D;
    float var  = sq / (float)D - mu * mu;
    float rstd = rsqrtf(var + EPS);
    int dest = perm[row];
    unsigned short* orow = (unsigned short*)xgb + (size_t)dest * D;
#pragma unroll
    for (int t = 0; t < 3; ++t) {
        int base = (lane + 64 * t) * 4;
        float4 g4 = *(const float4*)(gamma + base);
        float4 b4 = *(const float4*)(beta + base);
        float f0 = (v[t].x - mu) * rstd * g4.x + b4.x;
        float f1 = (v[t].y - mu) * rstd * g4.y + b4.y;
        float f2 = (v[t].z - mu) * rstd * g4.z + b4.z;
        float f3 = (v[t].w - mu) * rstd * g4.w + b4.w;
        __hip_bfloat16 h0 = __float2bfloat16(f0), h1 = __float2bfloat16(f1);
        __hip_bfloat16 h2 = __float2bfloat16(f2), h3 = __float2bfloat16(f3);
        ushort4 u;
        u.x = *(unsigned short*)&h0; u.y = *(unsigned short*)&h1;
        u.z = *(unsigned short*)&h2; u.w = *(unsigned short*)&h3;
        *(ushort4*)(orow + base) = u;
    }
}

// ---------------- K3v: cd rows, vectorized loads + cross-wave LDS reduce --------
__global__ __launch_bounds__(256) void k3_cd(const __hip_bfloat16* __restrict__ xgb,
        const float* __restrict__ cdic, const float* __restrict__ gamma,
        const float* __restrict__ beta, const int* __restrict__ counts,
        const int* __restrict__ gofs, float* __restrict__ cd) {
    int c = blockIdx.x + 1;      // 1..95
    int tid = threadIdx.x, wave = tid >> 6, lane = tid & 63;
    int n = counts[c];
    const unsigned short* rows = (const unsigned short*)xgb + (size_t)(gofs[c] + 1) * D;
    float acc[3][4];
#pragma unroll
    for (int p = 0; p < 3; ++p)
#pragma unroll
        for (int e = 0; e < 4; ++e) acc[p][e] = 0.f;
    // wave w handles rows w, w+4, ...; lane reads ushort4 (4 bf16) per 256-col band
    for (int r = wave; r < n; r += 4) {
        const unsigned short* rp = rows + (size_t)r * D + lane * 4;
#pragma unroll
        for (int p = 0; p < 3; ++p) {
            ushort4 u = *(const ushort4*)(rp + 256 * p);
            acc[p][0] += __bfloat162float(*(const __hip_bfloat16*)&u.x);
            acc[p][1] += __bfloat162float(*(const __hip_bfloat16*)&u.y);
            acc[p][2] += __bfloat162float(*(const __hip_bfloat16*)&u.z);
            acc[p][3] += __bfloat162float(*(const __hip_bfloat16*)&u.w);
        }
    }
    __shared__ float part[4][D];   // 12 KB
    __shared__ float red[8];
#pragma unroll
    for (int p = 0; p < 3; ++p)
#pragma unroll
        for (int e = 0; e < 4; ++e)
            part[wave][p * 256 + lane * 4 + e] = acc[p][e];
    __syncthreads();
    float s0 = (part[0][tid] + part[1][tid]) + (part[2][tid] + part[3][tid]);
    float s1 = (part[0][tid + 256] + part[1][tid + 256]) + (part[2][tid + 256] + part[3][tid + 256]);
    float s2 = (part[0][tid + 512] + part[1][tid + 512]) + (part[2][tid + 512] + part[3][tid + 512]);
    float invn = 1.f / ((float)n + 1.f);
    float c0 = cdic[c * D + tid], c1 = cdic[c * D + tid + 256], c2v = cdic[c * D + tid + 512];
    float u0 = c0 + 0.1f * (c0 + s0) * invn;
    float u1 = c1 + 0.1f * (c1 + s1) * invn;
    float u2 = c2v + 0.1f * (c2v + s2) * invn;
    float s = u0 + u1 + u2, sq = u0 * u0 + u1 * u1 + u2 * u2;
#pragma unroll
    for (int o = 32; o; o >>= 1) { s += __shfl_xor(s, o); sq += __shfl_xor(sq, o); }
    if (lane == 0) { red[wave] = s; red[4 + wave] = sq; }
    __syncthreads();
    if (tid == 0) {
        red[0] = red[0] + red[1] + red[2] + red[3];
        red[4] = red[4] + red[5] + red[6] + red[7];
    }
    __syncthreads();
    float mu   = red[0] / (float)D;
    float var  = red[4] / (float)D - mu * mu;
    float rstd = rsqrtf(var + EPS);
    float* outr = cd + (size_t)(c - 1) * D;
    outr[tid]       = (u0 - mu) * rstd * gamma[tid]       + beta[tid];
    outr[tid + 256] = (u1 - mu) * rstd * gamma[tid + 256] + beta[tid + 256];
    outr[tid + 512] = (u2 - mu) * rstd * gamma[tid + 512] + beta[tid + 512];
}

// ---------------- K4: positive gram via MFMA (round-3 proven) -------------------
__global__ __launch_bounds__(256) void k4_pos(const __hip_bfloat16* __restrict__ xgbh,
        const int* __restrict__ counts, const int* __restrict__ gofs,
        float* __restrict__ posp) {
    const unsigned short* xgb = (const unsigned short*)xgbh;
    int c = blockIdx.x;
    int tid = threadIdx.x, wave = tid >> 6, lane = tid & 63;
    extern __shared__ unsigned short sh[];
    int r0 = gofs[c];
    int nc = counts[c] + 1;
    int ntile = (nc + 31) >> 5;
    int nr = ntile << 5;
    int tott = ntile * (ntile + 1) / 2;
    int s_ti[4], s_tj[4];
#pragma unroll
    for (int slot = 0; slot < 4; ++slot) {
        int t = wave + slot * 4;
        int ti = 0, rem = t, span = ntile;
        if (t < tott) {
            while (rem >= span) { rem -= span; --span; ++ti; }
            s_ti[slot] = ti; s_tj[slot] = ti + rem;
        } else { s_ti[slot] = 0; s_tj[slot] = 0; }
    }
    int r16 = lane & 15, sA = lane >> 4;
    int xr = r16 & 7;
    int e0 = (sA ^ xr) * 8;
    int e1 = ((sA + 4) ^ xr) * 8;
    f32x4 acc[4][4];
#pragma unroll
    for (int s = 0; s < 4; ++s)
#pragma unroll
        for (int q = 0; q < 4; ++q) acc[s][q] = f32x4{0.f, 0.f, 0.f, 0.f};
    for (int kc = 0; kc < D; kc += KB) {
        __syncthreads();
        int totseg = nr * SEGR;
        for (int seg = tid; seg < totseg; seg += 256) {
            int r = seg / SEGR, s = seg - r * SEGR;
            uint4 v = {0u, 0u, 0u, 0u};
            if (r < nc)
                v = *(const uint4*)(xgb + (size_t)(r0 + r) * D + kc + s * 8);
            *(uint4*)(sh + r * KB + (s ^ (r & 7)) * 8) = v;
        }
        __syncthreads();
#pragma unroll
        for (int slot = 0; slot < 4; ++slot) {
            if (wave + slot * 4 >= tott) continue;
            int ti = s_ti[slot], tj = s_tj[slot];
            const unsigned short* pa0 = sh + (ti * 32 + r16) * KB;
            const unsigned short* pa1 = pa0 + 16 * KB;
            const unsigned short* pb0 = sh + (tj * 32 + r16) * KB;
            const unsigned short* pb1 = pb0 + 16 * KB;
#pragma unroll
            for (int ks = 0; ks < KB / 32; ++ks) {
                int ko = (ks >> 1) * 64 + ((ks & 1) ? e1 : e0);
                bf16x8 a0 = *(const bf16x8*)(pa0 + ko);
                bf16x8 a1 = *(const bf16x8*)(pa1 + ko);
                bf16x8 b0 = *(const bf16x8*)(pb0 + ko);
                bf16x8 b1 = *(const bf16x8*)(pb1 + ko);
                acc[slot][0] = __builtin_amdgcn_mfma_f32_16x16x32_bf16(a0, b0, acc[slot][0], 0, 0, 0);
                acc[slot][1] = __builtin_amdgcn_mfma_f32_16x16x32_bf16(a0, b1, acc[slot][1], 0, 0, 0);
                acc[slot][2] = __builtin_amdgcn_mfma_f32_16x16x32_bf16(a1, b0, acc[slot][2], 0, 0, 0);
                acc[slot][3] = __builtin_amdgcn_mfma_f32_16x16x32_bf16(a1, b1, acc[slot][3], 0, 0, 0);
            }
        }
    }
    const float inv = 1.f / (float)D;
    float tacc = 0.f;
    int rbase = sA * 4;
#pragma unroll
    for (int slot = 0; slot < 4; ++slot) {
        if (wave + slot * 4 >= tott) continue;
        int ti = s_ti[slot], tj = s_tj[slot];
        float w = (ti == tj) ? 1.f : 2.f;
#pragma unroll
        for (int fa = 0; fa < 2; ++fa)
#pragma unroll
            for (int fb = 0; fb < 2; ++fb)
#pragma unroll
                for (int reg = 0; reg < 4; ++reg) {
                    int i = ti * 32 + fa * 16 + rbase + reg;
                    int j = tj * 32 + fb * 16 + r16;
                    if (i < nc && j < nc)
                        tacc += w * __expf(acc[slot][fa * 2 + fb][reg] * inv);
                }
    }
#pragma unroll
    for (int o = 32; o; o >>= 1) tacc += __shfl_xor(tacc, o);
    __shared__ float red[4];
    if (lane == 0) red[wave] = tacc;
    __syncthreads();
    if (tid == 0) posp[c] = red[0] + red[1] + red[2] + red[3];
}

// ---------------- kC: neg gram + ticket-gated final loss (proven r6/r7) ---------
__global__ __launch_bounds__(256) void kC(const float* __restrict__ cd,
        const float* __restrict__ posp, unsigned int* __restrict__ negbits,
        unsigned int* __restrict__ ticket, float* __restrict__ out) {
    int i = blockIdx.x;    // 0..94
    int tid = threadIdx.x, wave = tid >> 6, lane = tid & 63;
    __shared__ float rowi[D];
    __shared__ float red[4];
    __shared__ int winner;
    for (int t = tid; t < D; t += 256) rowi[t] = cd[(size_t)i * D + t];
    __syncthreads();
    float acc = 0.f;
    for (int j = wave; j < 95; j += 4) {
        const float* rj = cd + (size_t)j * D;
        float dot = 0.f;
#pragma unroll
        for (int t = 0; t < 12; ++t) dot += rowi[lane + 64 * t] * rj[lane + 64 * t];
#pragma unroll
        for (int o = 32; o; o >>= 1) dot += __shfl_xor(dot, o);
        if (lane == 0) acc += __expf(dot * (1.f / (float)D));
    }
    if (lane == 0) red[wave] = acc;
    __syncthreads();
    if (tid == 0) {
        float val = red[0] + red[1] + red[2] + red[3];
        atomicExch(&negbits[i], __float_as_uint(val));   // device-scope publish
        __threadfence();
        winner = (atomicAdd(ticket, 1u) == 94u) ? 1 : 0; // 95th finisher wins
    }
    __syncthreads();
    if (winner && wave == 0) {
        __threadfence();                                 // acquire others' publishes
        double ng = (lane < 95)
            ? (double)__uint_as_float(atomicOr(&negbits[lane], 0u)) : 0.0;
        if (lane < 31)
            ng += (double)__uint_as_float(atomicOr(&negbits[64 + lane], 0u));
        double p = (double)posp[lane];
        if (lane < 32) p += (double)posp[64 + lane];
#pragma unroll
        for (int o = 32; o; o >>= 1) {
            ng += __shfl_xor(ng, o);
            p  += __shfl_xor(p, o);
        }
        if (lane == 0) out[0] = (float)(log(ng) - log(p));
    }
}

extern "C" void kernel_launch(void* const* d_in, const int* in_sizes, int n_in,
                              void* d_out, int out_size, void* d_ws, size_t ws_size,
                              hipStream_t stream) {
    const float* input_f  = (const float*)d_in[0];
    const float* char_dic = (const float*)d_in[1];
    const float* gamma    = (const float*)d_in[2];
    const float* beta     = (const float*)d_in[3];
    const int*   target   = (const int*)d_in[4];
    float* out = (float*)d_out;

    char* ws = (char*)d_ws;
    size_t off = 0;
    auto carve = [&](size_t bytes) -> void* {
        void* p = ws + off;
        off = (off + bytes + 255) & ~(size_t)255;
        return p;
    };
    __hip_bfloat16* xgb = (__hip_bfloat16*)carve((size_t)(NROWS + 32) * D * 2); // 12.8 MB
    int*          perm    = (int*)  carve((size_t)M * 4);
    int*          counts  = (int*)  carve(NCLS * 4);
    int*          gofs    = (int*)  carve(NCLS * 4);
    float*        posp    = (float*)carve(NCLS * 4);
    float*        cd      = (float*)carve((size_t)95 * D * 4);
    unsigned int* negbits = (unsigned int*)carve(95 * 4);
    unsigned int* ticket  = (unsigned int*)carve(64);

    (void)hipFuncSetAttribute((const void*)k4_pos,
            hipFuncAttributeMaxDynamicSharedMemorySize, DYN_B);

    k2_lists<<<NCLS, 256, 0, stream>>>(target, char_dic, perm, counts, gofs, xgb, ticket);
    k1_layernorm<<<M / 4, 256, 0, stream>>>(input_f, gamma, beta, perm, xgb);
    k4_pos<<<NCLS, 256, DYN_B, stream>>>(xgb, counts, gofs, posp);
    k3_cd<<<95, 256, 0, stream>>>(xgb, char_dic, gamma, beta, counts, gofs, cd);
    kC<<<95, 256, 0, stream>>>(cd, posp, negbits, ticket, out);
}

// Round 9
// 62.035 us; speedup vs baseline: 7.4494x; 1.1647x over previous
//
#include <hip/hip_runtime.h>
#include <hip/hip_bf16.h>
#include <math.h>

#define D 768
#define NCLS 96
#define M 8192            // 32*256 tokens
#define NROWS (M + NCLS)  // 8288 grouped rows
#define EPS 1e-5f

// gram geometry (proven round-3)
#define KB 384
#define SEGR 48           // KB/8 16B segments per row-chunk
#define MAXR 160          // max rows per class (dict + tokens)
#define DYN_B (MAXR * KB * 2)   // 122880 B dynamic LDS

typedef __attribute__((ext_vector_type(8))) short bf16x8;
typedef __attribute__((ext_vector_type(4))) float f32x4;

// ---------------- K2: counts/gofs/perm + dict copy (round-3 proven) -------------
__global__ __launch_bounds__(256) void k2_lists(const int* __restrict__ labels,
        const float* __restrict__ cdic, int* __restrict__ perm,
        int* __restrict__ counts, int* __restrict__ gofs,
        __hip_bfloat16* __restrict__ xgb, unsigned int* __restrict__ ticket) {
    int c = blockIdx.x;
    int tid = threadIdx.x, wave = tid >> 6, lane = tid & 63;
    __shared__ int labs[M];
    __shared__ int ccnt[128];
    __shared__ int cbase[128];
    __shared__ int ltred[4];
    __shared__ int gsh;
    if (c == 0 && tid == 0) *ticket = 0u;     // reset finish ticket each call
    for (int t = tid; t < M / 4; t += 256)
        ((int4*)labs)[t] = ((const int4*)labels)[t];
    __syncthreads();
    int lt0 = 0;
    for (int ch = wave; ch < 128; ch += 4) {
        int lab = labs[ch * 64 + lane];
        unsigned long long meq = __ballot(lab == c);
        unsigned long long mlt = __ballot(lab < c);
        if (lane == 0) { ccnt[ch] = __popcll(meq); lt0 += __popcll(mlt); }
    }
    if (lane == 0) ltred[wave] = lt0;
    __syncthreads();
    if (wave == 0) {
        int v0 = ccnt[lane], v1 = ccnt[64 + lane];
        int s0 = v0;
#pragma unroll
        for (int o = 1; o < 64; o <<= 1) { int t0 = __shfl_up(s0, o); if (lane >= o) s0 += t0; }
        int tot0 = __shfl(s0, 63);
        int s1 = v1;
#pragma unroll
        for (int o = 1; o < 64; o <<= 1) { int t1 = __shfl_up(s1, o); if (lane >= o) s1 += t1; }
        cbase[lane] = s0 - v0;
        cbase[64 + lane] = tot0 + s1 - v1;
        if (lane == 63) {
            counts[c] = tot0 + s1;
            int g = c + ltred[0] + ltred[1] + ltred[2] + ltred[3];
            gofs[c] = g;
            gsh = g;
        }
    }
    __syncthreads();
    int g = gsh;
    for (int ch = wave; ch < 128; ch += 4) {
        int m = ch * 64 + lane;
        bool match = (labs[m] == c);
        unsigned long long mask = __ballot(match);
        int pre = __popcll(mask & ((1ull << lane) - 1ull));
        if (match) perm[m] = g + 1 + cbase[ch] + pre;
    }
    for (int t = tid; t < D; t += 256)
        xgb[(size_t)g * D + t] = __float2bfloat16(cdic[c * D + t]);
}

// ---------------- K1: LayerNorm + bf16 scatter (round-3 proven) -----------------
__global__ __launch_bounds__(256) void k1_layernorm(const float* __restrict__ x,
        const float* __restrict__ gamma, const float* __restrict__ beta,
        const int* __restrict__ perm, __hip_bfloat16* __restrict__ xgb) {
    int wave = threadIdx.x >> 6;
    int lane = threadIdx.x & 63;
    int row = blockIdx.x * 4 + wave;
    const float* xr = x + (size_t)row * D;
    float4 v[3];
    float s = 0.f, sq = 0.f;
#pragma unroll
    for (int t = 0; t < 3; ++t) {
        v[t] = *(const float4*)(xr + (lane + 64 * t) * 4);
        s  += v[t].x + v[t].y + v[t].z + v[t].w;
        sq += v[t].x * v[t].x + v[t].y * v[t].y + v[t].z * v[t].z + v[t].w * v[t].w;
    }
#pragma unroll
    for (int o = 32; o; o >>= 1) { s += __shfl_xor(s, o); sq += __shfl_xor(sq, o); }
    float mu   = s / (float)D;
    float var  = sq / (float)D - mu * mu;
    float rstd = rsqrtf(var + EPS);
    int dest = perm[row];
    unsigned short* orow = (unsigned short*)xgb + (size_t)dest * D;
#pragma unroll
    for (int t = 0; t < 3; ++t) {
        int base = (lane + 64 * t) * 4;
        float4 g4 = *(const float4*)(gamma + base);
        float4 b4 = *(const float4*)(beta + base);
        float f0 = (v[t].x - mu) * rstd * g4.x + b4.x;
        float f1 = (v[t].y - mu) * rstd * g4.y + b4.y;
        float f2 = (v[t].z - mu) * rstd * g4.z + b4.z;
        float f3 = (v[t].w - mu) * rstd * g4.w + b4.w;
        __hip_bfloat16 h0 = __float2bfloat16(f0), h1 = __float2bfloat16(f1);
        __hip_bfloat16 h2 = __float2bfloat16(f2), h3 = __float2bfloat16(f3);
        ushort4 u;
        u.x = *(unsigned short*)&h0; u.y = *(unsigned short*)&h1;
        u.z = *(unsigned short*)&h2; u.w = *(unsigned short*)&h3;
        *(ushort4*)(orow + base) = u;
    }
}

// ---------------- kB: gram (blocks 0..95) || cd (blocks 96..190) ----------------
// Both halves depend only on xgb (k1); mutually independent -> real CU overlap.
__global__ __launch_bounds__(256) void kB(const __hip_bfloat16* __restrict__ xgbh,
        const float* __restrict__ cdic, const float* __restrict__ gamma,
        const float* __restrict__ beta, const int* __restrict__ counts,
        const int* __restrict__ gofs, float* __restrict__ posp,
        float* __restrict__ cd) {
    int bid = blockIdx.x, tid = threadIdx.x, wave = tid >> 6, lane = tid & 63;

    if (bid < NCLS) {
        // -------- positive gram (round-3 proven k4 body) --------
        const unsigned short* xgb = (const unsigned short*)xgbh;
        int c = bid;
        extern __shared__ unsigned short sh[];
        int r0 = gofs[c];
        int nc = counts[c] + 1;
        int ntile = (nc + 31) >> 5;
        int nr = ntile << 5;
        int tott = ntile * (ntile + 1) / 2;
        int s_ti[4], s_tj[4];
#pragma unroll
        for (int slot = 0; slot < 4; ++slot) {
            int t = wave + slot * 4;
            int ti = 0, rem = t, span = ntile;
            if (t < tott) {
                while (rem >= span) { rem -= span; --span; ++ti; }
                s_ti[slot] = ti; s_tj[slot] = ti + rem;
            } else { s_ti[slot] = 0; s_tj[slot] = 0; }
        }
        int r16 = lane & 15, sA = lane >> 4;
        int xr = r16 & 7;
        int e0 = (sA ^ xr) * 8;
        int e1 = ((sA + 4) ^ xr) * 8;
        f32x4 acc[4][4];
#pragma unroll
        for (int s = 0; s < 4; ++s)
#pragma unroll
            for (int q = 0; q < 4; ++q) acc[s][q] = f32x4{0.f, 0.f, 0.f, 0.f};
        for (int kc = 0; kc < D; kc += KB) {
            __syncthreads();
            int totseg = nr * SEGR;
            for (int seg = tid; seg < totseg; seg += 256) {
                int r = seg / SEGR, s = seg - r * SEGR;
                uint4 v = {0u, 0u, 0u, 0u};
                if (r < nc)
                    v = *(const uint4*)(xgb + (size_t)(r0 + r) * D + kc + s * 8);
                *(uint4*)(sh + r * KB + (s ^ (r & 7)) * 8) = v;
            }
            __syncthreads();
#pragma unroll
            for (int slot = 0; slot < 4; ++slot) {
                if (wave + slot * 4 >= tott) continue;
                int ti = s_ti[slot], tj = s_tj[slot];
                const unsigned short* pa0 = sh + (ti * 32 + r16) * KB;
                const unsigned short* pa1 = pa0 + 16 * KB;
                const unsigned short* pb0 = sh + (tj * 32 + r16) * KB;
                const unsigned short* pb1 = pb0 + 16 * KB;
#pragma unroll
                for (int ks = 0; ks < KB / 32; ++ks) {
                    int ko = (ks >> 1) * 64 + ((ks & 1) ? e1 : e0);
                    bf16x8 a0 = *(const bf16x8*)(pa0 + ko);
                    bf16x8 a1 = *(const bf16x8*)(pa1 + ko);
                    bf16x8 b0 = *(const bf16x8*)(pb0 + ko);
                    bf16x8 b1 = *(const bf16x8*)(pb1 + ko);
                    acc[slot][0] = __builtin_amdgcn_mfma_f32_16x16x32_bf16(a0, b0, acc[slot][0], 0, 0, 0);
                    acc[slot][1] = __builtin_amdgcn_mfma_f32_16x16x32_bf16(a0, b1, acc[slot][1], 0, 0, 0);
                    acc[slot][2] = __builtin_amdgcn_mfma_f32_16x16x32_bf16(a1, b0, acc[slot][2], 0, 0, 0);
                    acc[slot][3] = __builtin_amdgcn_mfma_f32_16x16x32_bf16(a1, b1, acc[slot][3], 0, 0, 0);
                }
            }
        }
        const float inv = 1.f / (float)D;
        float tacc = 0.f;
        int rbase = sA * 4;
#pragma unroll
        for (int slot = 0; slot < 4; ++slot) {
            if (wave + slot * 4 >= tott) continue;
            int ti = s_ti[slot], tj = s_tj[slot];
            float w = (ti == tj) ? 1.f : 2.f;
#pragma unroll
            for (int fa = 0; fa < 2; ++fa)
#pragma unroll
                for (int fb = 0; fb < 2; ++fb)
#pragma unroll
                    for (int reg = 0; reg < 4; ++reg) {
                        int i = ti * 32 + fa * 16 + rbase + reg;
                        int j = tj * 32 + fb * 16 + r16;
                        if (i < nc && j < nc)
                            tacc += w * __expf(acc[slot][fa * 2 + fb][reg] * inv);
                    }
        }
#pragma unroll
        for (int o = 32; o; o >>= 1) tacc += __shfl_xor(tacc, o);
        __syncthreads();
        float* red = (float*)sh;
        if (lane == 0) red[wave] = tacc;
        __syncthreads();
        if (tid == 0) posp[c] = red[0] + red[1] + red[2] + red[3];
    } else {
        // -------- cd rows (round-8 proven k3v body), c = bid-95 in 1..95 --------
        int c = bid - 95;
        int n = counts[c];
        const unsigned short* rows = (const unsigned short*)xgbh + (size_t)(gofs[c] + 1) * D;
        float acc[3][4];
#pragma unroll
        for (int p = 0; p < 3; ++p)
#pragma unroll
            for (int e = 0; e < 4; ++e) acc[p][e] = 0.f;
        for (int r = wave; r < n; r += 4) {
            const unsigned short* rp = rows + (size_t)r * D + lane * 4;
#pragma unroll
            for (int p = 0; p < 3; ++p) {
                ushort4 u = *(const ushort4*)(rp + 256 * p);
                acc[p][0] += __bfloat162float(*(const __hip_bfloat16*)&u.x);
                acc[p][1] += __bfloat162float(*(const __hip_bfloat16*)&u.y);
                acc[p][2] += __bfloat162float(*(const __hip_bfloat16*)&u.z);
                acc[p][3] += __bfloat162float(*(const __hip_bfloat16*)&u.w);
            }
        }
        __shared__ float part[4][D];   // 12 KB static (separate from dynamic sh)
        __shared__ float red[8];
#pragma unroll
        for (int p = 0; p < 3; ++p)
#pragma unroll
            for (int e = 0; e < 4; ++e)
                part[wave][p * 256 + lane * 4 + e] = acc[p][e];
        __syncthreads();
        float s0 = (part[0][tid] + part[1][tid]) + (part[2][tid] + part[3][tid]);
        float s1 = (part[0][tid + 256] + part[1][tid + 256]) + (part[2][tid + 256] + part[3][tid + 256]);
        float s2 = (part[0][tid + 512] + part[1][tid + 512]) + (part[2][tid + 512] + part[3][tid + 512]);
        float invn = 1.f / ((float)n + 1.f);
        float c0 = cdic[c * D + tid], c1 = cdic[c * D + tid + 256], c2v = cdic[c * D + tid + 512];
        float u0 = c0 + 0.1f * (c0 + s0) * invn;
        float u1 = c1 + 0.1f * (c1 + s1) * invn;
        float u2 = c2v + 0.1f * (c2v + s2) * invn;
        float s = u0 + u1 + u2, sq = u0 * u0 + u1 * u1 + u2 * u2;
#pragma unroll
        for (int o = 32; o; o >>= 1) { s += __shfl_xor(s, o); sq += __shfl_xor(sq, o); }
        if (lane == 0) { red[wave] = s; red[4 + wave] = sq; }
        __syncthreads();
        if (tid == 0) {
            red[0] = red[0] + red[1] + red[2] + red[3];
            red[4] = red[4] + red[5] + red[6] + red[7];
        }
        __syncthreads();
        float mu   = red[0] / (float)D;
        float var  = red[4] / (float)D - mu * mu;
        float rstd = rsqrtf(var + EPS);
        float* outr = cd + (size_t)(c - 1) * D;
        outr[tid]       = (u0 - mu) * rstd * gamma[tid]       + beta[tid];
        outr[tid + 256] = (u1 - mu) * rstd * gamma[tid + 256] + beta[tid + 256];
        outr[tid + 512] = (u2 - mu) * rstd * gamma[tid + 512] + beta[tid + 512];
    }
}

// ---------------- kC: neg gram + ticket-gated final loss (proven r6-r8) ---------
__global__ __launch_bounds__(256) void kC(const float* __restrict__ cd,
        const float* __restrict__ posp, unsigned int* __restrict__ negbits,
        unsigned int* __restrict__ ticket, float* __restrict__ out) {
    int i = blockIdx.x;    // 0..94
    int tid = threadIdx.x, wave = tid >> 6, lane = tid & 63;
    __shared__ float rowi[D];
    __shared__ float red[4];
    __shared__ int winner;
    for (int t = tid; t < D; t += 256) rowi[t] = cd[(size_t)i * D + t];
    __syncthreads();
    float acc = 0.f;
    for (int j = wave; j < 95; j += 4) {
        const float* rj = cd + (size_t)j * D;
        float dot = 0.f;
#pragma unroll
        for (int t = 0; t < 12; ++t) dot += rowi[lane + 64 * t] * rj[lane + 64 * t];
#pragma unroll
        for (int o = 32; o; o >>= 1) dot += __shfl_xor(dot, o);
        if (lane == 0) acc += __expf(dot * (1.f / (float)D));
    }
    if (lane == 0) red[wave] = acc;
    __syncthreads();
    if (tid == 0) {
        float val = red[0] + red[1] + red[2] + red[3];
        atomicExch(&negbits[i], __float_as_uint(val));   // device-scope publish
        __threadfence();
        winner = (atomicAdd(ticket, 1u) == 94u) ? 1 : 0; // 95th finisher wins
    }
    __syncthreads();
    if (winner && wave == 0) {
        __threadfence();                                 // acquire others' publishes
        double ng = (lane < 95)
            ? (double)__uint_as_float(atomicOr(&negbits[lane], 0u)) : 0.0;
        if (lane < 31)
            ng += (double)__uint_as_float(atomicOr(&negbits[64 + lane], 0u));
        double p = (double)posp[lane];
        if (lane < 32) p += (double)posp[64 + lane];
#pragma unroll
        for (int o = 32; o; o >>= 1) {
            ng += __shfl_xor(ng, o);
            p  += __shfl_xor(p, o);
        }
        if (lane == 0) out[0] = (float)(log(ng) - log(p));
    }
}

extern "C" void kernel_launch(void* const* d_in, const int* in_sizes, int n_in,
                              void* d_out, int out_size, void* d_ws, size_t ws_size,
                              hipStream_t stream) {
    const float* input_f  = (const float*)d_in[0];
    const float* char_dic = (const float*)d_in[1];
    const float* gamma    = (const float*)d_in[2];
    const float* beta     = (const float*)d_in[3];
    const int*   target   = (const int*)d_in[4];
    float* out = (float*)d_out;

    char* ws = (char*)d_ws;
    size_t off = 0;
    auto carve = [&](size_t bytes) -> void* {
        void* p = ws + off;
        off = (off + bytes + 255) & ~(size_t)255;
        return p;
    };
    __hip_bfloat16* xgb = (__hip_bfloat16*)carve((size_t)(NROWS + 32) * D * 2); // 12.8 MB
    int*          perm    = (int*)  carve((size_t)M * 4);
    int*          counts  = (int*)  carve(NCLS * 4);
    int*          gofs    = (int*)  carve(NCLS * 4);
    float*        posp    = (float*)carve(NCLS * 4);
    float*        cd      = (float*)carve((size_t)95 * D * 4);
    unsigned int* negbits = (unsigned int*)carve(95 * 4);
    unsigned int* ticket  = (unsigned int*)carve(64);

    (void)hipFuncSetAttribute((const void*)kB,
            hipFuncAttributeMaxDynamicSharedMemorySize, DYN_B);

    k2_lists<<<NCLS, 256, 0, stream>>>(target, char_dic, perm, counts, gofs, xgb, ticket);
    k1_layernorm<<<M / 4, 256, 0, stream>>>(input_f, gamma, beta, perm, xgb);
    kB<<<NCLS + 95, 256, DYN_B, stream>>>(xgb, char_dic, gamma, beta, counts, gofs, posp, cd);
    kC<<<95, 256, 0, stream>>>(cd, posp, negbits, ticket, out);
}